// Round 2
// baseline (1502.417 us; speedup 1.0000x reference)
//
#include <hip/hip_runtime.h>
#include <hip/hip_bf16.h>
#include <math.h>

namespace {
constexpr int B_ = 4, HQ_ = 32, HK_ = 8, G_ = 4, M_ = 16;
constexpr int N_ = 8192, D_ = 128, S_ = 256, O_ = 8;
constexpr int TN = 64;               // n-rows per block
constexpr float TAU = 2e-3f;         // |dot| below this -> fp64 sign recheck
}

// ---------------- kernel A: sqT = (q · P)^T per head  ([B*HQ][S][M], fp32) ----------------
__global__ __launch_bounds__(256) void qjl_sketch_q(const float* __restrict__ q,
                                                    const float* __restrict__ P,
                                                    float* __restrict__ sq) {
    __shared__ float qs[M_][D_];
    const int tid = threadIdx.x;
    const size_t blk = blockIdx.x;  // b*HQ + hq
    const float* qb = q + blk * (size_t)(M_ * D_);
    for (int i = tid; i < M_ * D_ / 4; i += 256)
        reinterpret_cast<float4*>(&qs[0][0])[i] = reinterpret_cast<const float4*>(qb)[i];
    __syncthreads();
    float acc[M_];
#pragma unroll
    for (int m = 0; m < M_; ++m) acc[m] = 0.f;
    const int s = tid;  // 256 threads == 256 s columns
    for (int d = 0; d < D_; ++d) {
        const float pv = P[d * S_ + s];
#pragma unroll
        for (int m = 0; m < M_; ++m) acc[m] = fmaf(qs[m][d], pv, acc[m]);
    }
    // transposed store: [s][m], 64B contiguous per thread
    float* ob = sq + blk * (size_t)(M_ * S_) + (size_t)s * M_;
#pragma unroll
    for (int m4 = 0; m4 < M_ / 4; ++m4) {
        float4 v;
        v.x = acc[4 * m4 + 0]; v.y = acc[4 * m4 + 1];
        v.z = acc[4 * m4 + 2]; v.w = acc[4 * m4 + 3];
        reinterpret_cast<float4*>(ob)[m4] = v;
    }
}

// rare path: exact-sign recompute in fp64 (drow is an LDS row, P column scol)
__device__ __noinline__ float qjl_fixsign(const float* drow, const float* __restrict__ P,
                                          int scol) {
    double s = 0.0;
    for (int d = 0; d < D_; ++d)
        s = fma((double)drow[d], (double)P[(size_t)d * S_ + scol], s);
    return (s > 0.0) ? 1.f : -1.f;
}

// ---------------- kernel B: main ----------------
// grid (N/TN, HK, B), block 256 (4 waves). Wave w owns rows [16w,16w+16) for the
// sign matmul and head g=w for the output phase; lane l owns s in {l,l+64,l+128,l+192}.
__global__ __launch_bounds__(256, 4) void qjl_main(const float* __restrict__ data,
                                                   const float* __restrict__ q,
                                                   const float* __restrict__ P,
                                                   const int* __restrict__ oidx,
                                                   const float* __restrict__ sq,
                                                   float* __restrict__ out) {
    __shared__ float sdata[TN][D_];              // 32 KB, outliers zeroed in place
    __shared__ union {                            // 2 KB, phase-disjoint (barrier-separated)
        float svals[TN][O_];                      //   phases A,B: original outlier values
        unsigned long long sbits[TN][4];          //   phases C,D: sign_in bitmasks
    } uo;
    __shared__ int   sidxs[TN][O_];               // dedup'd indices (-1 = dup slot)
    __shared__ float su[TN][O_];                  // u_j per row
    __shared__ float sfull[TN];                   // full row sum-of-squares
    __shared__ float snin[TN];                    // c_in  * ||k_in||
    __shared__ float snout[TN];                   // c_out * ||k_out||

    const int tid = threadIdx.x;
    const int lane = tid & 63;
    const int wv = tid >> 6;
    const int nt = blockIdx.x, hk = blockIdx.y, b = blockIdx.z;
    const int n0 = nt * TN;

    // ---- phase 0: load data tile (+ per-row sumsq) ----
    {
        const int r = tid >> 2;  // row 0..63
        const int c = tid & 3;
        const float* drow = data + ((size_t)(b * HK_ + hk) * N_ + n0 + r) * D_;
        float ssq = 0.f;
#pragma unroll
        for (int k = 0; k < 8; ++k) {
            const int f = c + 4 * k;
            float4 v = reinterpret_cast<const float4*>(drow)[f];
            reinterpret_cast<float4*>(&sdata[r][0])[f] = v;
            ssq += v.x * v.x + v.y * v.y + v.z * v.z + v.w * v.w;
        }
        ssq += __shfl_xor(ssq, 1);
        ssq += __shfl_xor(ssq, 2);
        if (c == 0) sfull[r] = ssq;
    }
    __syncthreads();

    // ---- phase A: dedup outliers, record values, zero them in sdata, norms ----
    if (tid < TN) {
        const int n = tid;
        const int* ob = oidx + ((size_t)(b * HK_ + hk) * N_ + n0 + n) * O_;
        int id[O_];
        int4 i0 = reinterpret_cast<const int4*>(ob)[0];
        int4 i1 = reinterpret_cast<const int4*>(ob)[1];
        id[0] = i0.x; id[1] = i0.y; id[2] = i0.z; id[3] = i0.w;
        id[4] = i1.x; id[5] = i1.y; id[6] = i1.z; id[7] = i1.w;
        float so2 = 0.f;
#pragma unroll
        for (int j = 0; j < O_; ++j) {
            bool dup = false;
#pragma unroll
            for (int jj = 0; jj < O_; ++jj)
                if (jj < j) dup = dup || (id[jj] == id[j]);
            if (!dup) {
                const float v = sdata[n][id[j]];
                uo.svals[n][j] = v;
                sidxs[n][j] = id[j];
                so2 = fmaf(v, v, so2);
                sdata[n][id[j]] = 0.f;  // sdata now holds k_in exactly
            } else {
                uo.svals[n][j] = 0.f;
                sidxs[n][j] = -1;
            }
        }
        const float CIN = (float)(1.2533141373155003 / 256.0);   // sqrt(pi/2)/S
        const float COUT = (float)(1.2533141373155003 / 64.0);   // sqrt(pi/2)/SO
        snin[n] = CIN * sqrtf(fmaxf(sfull[n] - so2, 0.f));
        snout[n] = COUT * sqrtf(so2);
    }
    __syncthreads();

    // ---- phase B: sign_out (fp64 dot) and u_j; 4 threads per row ----
    {
        const int n = tid >> 2;
        const int c = tid & 3;
        float u[O_];
        float vv[O_];
        int idc[O_];
#pragma unroll
        for (int j = 0; j < O_; ++j) {
            u[j] = 0.f;
            const int ix = sidxs[n][j];
            idc[j] = (ix >= 0) ? ix : 0;  // clamp dups; their u is never used
            vv[j] = uo.svals[n][j];       // dups carry 0 -> no effect on cs
        }
        for (int t = c * 16; t < c * 16 + 16; ++t) {
            double cs = 0.0;
#pragma unroll
            for (int j = 0; j < O_; ++j)
                cs = fma((double)vv[j], (double)P[idc[j] * S_ + t], cs);
            const float sg = (cs > 0.0) ? 1.f : ((cs < 0.0) ? -1.f : 0.f);
#pragma unroll
            for (int j = 0; j < O_; ++j)
                u[j] = fmaf(sg, P[idc[j] * S_ + t], u[j]);
        }
#pragma unroll
        for (int j = 0; j < O_; ++j) {
            u[j] += __shfl_xor(u[j], 1);
            u[j] += __shfl_xor(u[j], 2);
        }
        if (c == 0) {
#pragma unroll
            for (int j = 0; j < O_; ++j) su[n][j] = u[j];
        }
    }
    __syncthreads();  // svals reads (B) complete before sbits writes (C); su visible to D

    // ---- phase C: G = k_in · P, fp32 acc + tau-guarded fp64 sign fixup; pack bits ----
    {
        float acc[16][4];
#pragma unroll
        for (int r = 0; r < 16; ++r)
#pragma unroll
            for (int k = 0; k < 4; ++k) acc[r][k] = 0.f;

        const float* Pl = P + lane;  // coalesced: lane l reads columns 64k+l
        for (int dc = 0; dc < D_; dc += 4) {
            const float* Pb = Pl + (size_t)dc * S_;
            float pv[4][4];
#pragma unroll
            for (int i = 0; i < 4; ++i)
#pragma unroll
                for (int k = 0; k < 4; ++k) pv[i][k] = Pb[i * S_ + 64 * k];
#pragma unroll
            for (int r = 0; r < 16; ++r) {
                const float4 dv = *reinterpret_cast<const float4*>(&sdata[wv * 16 + r][dc]);
#pragma unroll
                for (int k = 0; k < 4; ++k) {
                    float a = acc[r][k];
                    a = fmaf(dv.x, pv[0][k], a);
                    a = fmaf(dv.y, pv[1][k], a);
                    a = fmaf(dv.z, pv[2][k], a);
                    a = fmaf(dv.w, pv[3][k], a);
                    acc[r][k] = a;
                }
            }
        }
#pragma unroll
        for (int r = 0; r < 16; ++r) {
            unsigned long long bb[4];
#pragma unroll
            for (int k = 0; k < 4; ++k) {
                float a = acc[r][k];
                if (__ballot(fabsf(a) < TAU) != 0ull) {   // rare: ~2 cells per block
                    if (fabsf(a) < TAU)
                        a = qjl_fixsign(&sdata[wv * 16 + r][0], P, 64 * k + lane);
                }
                bb[k] = __ballot(a > 0.f);
            }
            if (lane == 0) {
#pragma unroll
                for (int k = 0; k < 4; ++k) uo.sbits[wv * 16 + r][k] = bb[k];
            }
        }
    }
    __syncthreads();

    // ---- phase D: part1 (bit-signed sum of sqT) + part2 (sparse outlier dot) + store ----
    {
        const int n = lane;           // row within tile
        const int hq = hk * G_ + wv;  // wave owns one head of the group
        const float* qrow = q + (size_t)(b * HQ_ + hq) * (M_ * D_);
        float accO[M_];
#pragma unroll
        for (int m = 0; m < M_; ++m) accO[m] = 0.f;
        const float cno = snout[n];
#pragma unroll
        for (int j = 0; j < O_; ++j) {
            const int ix = sidxs[n][j];
            const int ixc = (ix >= 0) ? ix : 0;
            const float uj = (ix >= 0) ? su[n][j] * cno : 0.f;
#pragma unroll
            for (int m = 0; m < M_; ++m)
                accO[m] = fmaf(uj, qrow[m * D_ + ixc], accO[m]);
        }

        unsigned long long bw[4];
#pragma unroll
        for (int k = 0; k < 4; ++k) bw[k] = uo.sbits[n][k];

        const float* sqb = sq + (size_t)(b * HQ_ + hq) * (M_ * S_);  // [s][m] layout
        float accI[M_];
#pragma unroll
        for (int m = 0; m < M_; ++m) accI[m] = 0.f;
        for (int k = 0; k < 4; ++k) {
            const unsigned long long w64 = bw[k];
            const float* sb_base = sqb + (size_t)k * 64 * M_;
            for (int sb = 0; sb < 64; ++sb) {
                const unsigned flip = (((unsigned)(w64 >> sb)) & 1u) ^ 1u;  // bit=1 -> +
                const unsigned msk = flip << 31;
                const float4* sp = reinterpret_cast<const float4*>(sb_base + sb * M_);
                const float4 v0 = sp[0], v1 = sp[1], v2 = sp[2], v3 = sp[3];
                accI[0]  += __uint_as_float(__float_as_uint(v0.x) ^ msk);
                accI[1]  += __uint_as_float(__float_as_uint(v0.y) ^ msk);
                accI[2]  += __uint_as_float(__float_as_uint(v0.z) ^ msk);
                accI[3]  += __uint_as_float(__float_as_uint(v0.w) ^ msk);
                accI[4]  += __uint_as_float(__float_as_uint(v1.x) ^ msk);
                accI[5]  += __uint_as_float(__float_as_uint(v1.y) ^ msk);
                accI[6]  += __uint_as_float(__float_as_uint(v1.z) ^ msk);
                accI[7]  += __uint_as_float(__float_as_uint(v1.w) ^ msk);
                accI[8]  += __uint_as_float(__float_as_uint(v2.x) ^ msk);
                accI[9]  += __uint_as_float(__float_as_uint(v2.y) ^ msk);
                accI[10] += __uint_as_float(__float_as_uint(v2.z) ^ msk);
                accI[11] += __uint_as_float(__float_as_uint(v2.w) ^ msk);
                accI[12] += __uint_as_float(__float_as_uint(v3.x) ^ msk);
                accI[13] += __uint_as_float(__float_as_uint(v3.y) ^ msk);
                accI[14] += __uint_as_float(__float_as_uint(v3.z) ^ msk);
                accI[15] += __uint_as_float(__float_as_uint(v3.w) ^ msk);
            }
        }

        const float cni = snin[n];
        float* ob = out + ((size_t)(b * HQ_ + hq) * N_ + (n0 + n)) * M_;
#pragma unroll
        for (int m4 = 0; m4 < M_ / 4; ++m4) {
            float4 v;
            v.x = fmaf(accI[4 * m4 + 0], cni, accO[4 * m4 + 0]);
            v.y = fmaf(accI[4 * m4 + 1], cni, accO[4 * m4 + 1]);
            v.z = fmaf(accI[4 * m4 + 2], cni, accO[4 * m4 + 2]);
            v.w = fmaf(accI[4 * m4 + 3], cni, accO[4 * m4 + 3]);
            reinterpret_cast<float4*>(ob)[m4] = v;
        }
    }
}

extern "C" void kernel_launch(void* const* d_in, const int* in_sizes, int n_in,
                              void* d_out, int out_size, void* d_ws, size_t ws_size,
                              hipStream_t stream) {
    const float* query = (const float*)d_in[0];  // [B][HQ][M][D]
    const float* data  = (const float*)d_in[1];  // [B][HK][N][D]
    const float* proj  = (const float*)d_in[2];  // [D][S]
    const int*   oidx  = (const int*)d_in[3];    // [B][HK][N][O]
    // d_in[4] = dim_outlier scalar (=64), baked in as SO

    float* out = (float*)d_out;                  // [B][HQ][N][M]
    float* sq = (float*)d_ws;                    // B*HQ*S*M floats = 2 MB scratch (transposed)

    qjl_sketch_q<<<dim3(B_ * HQ_), dim3(256), 0, stream>>>(query, proj, sq);
    qjl_main<<<dim3(N_ / TN, HK_, B_), dim3(256), 0, stream>>>(data, query, proj, oidx, sq, out);
}

// Round 3
// 633.068 us; speedup vs baseline: 2.3732x; 2.3732x over previous
//
#include <hip/hip_runtime.h>
#include <hip/hip_bf16.h>
#include <math.h>

namespace {
constexpr int B_ = 4, HQ_ = 32, HK_ = 8, G_ = 4, M_ = 16;
constexpr int N_ = 8192, D_ = 128, S_ = 256, O_ = 8;
constexpr int TN = 64;               // n-rows per block
constexpr float TAU = 2e-3f;         // |dot| below this -> fp64 sign recheck
}

// ---------------- kernel A: sqT = (q · P)^T per head  ([B*HQ][S][M], fp32) ----------------
__global__ __launch_bounds__(256) void qjl_sketch_q(const float* __restrict__ q,
                                                    const float* __restrict__ P,
                                                    float* __restrict__ sq) {
    __shared__ float qs[M_][D_];
    const int tid = threadIdx.x;
    const size_t blk = blockIdx.x;  // b*HQ + hq
    const float* qb = q + blk * (size_t)(M_ * D_);
    for (int i = tid; i < M_ * D_ / 4; i += 256)
        reinterpret_cast<float4*>(&qs[0][0])[i] = reinterpret_cast<const float4*>(qb)[i];
    __syncthreads();
    float acc[M_];
#pragma unroll
    for (int m = 0; m < M_; ++m) acc[m] = 0.f;
    const int s = tid;  // 256 threads == 256 s columns
    for (int d = 0; d < D_; ++d) {
        const float pv = P[d * S_ + s];
#pragma unroll
        for (int m = 0; m < M_; ++m) acc[m] = fmaf(qs[m][d], pv, acc[m]);
    }
    // transposed store: [s][m], 64B contiguous per thread
    float* ob = sq + blk * (size_t)(M_ * S_) + (size_t)s * M_;
#pragma unroll
    for (int m4 = 0; m4 < M_ / 4; ++m4) {
        float4 v;
        v.x = acc[4 * m4 + 0]; v.y = acc[4 * m4 + 1];
        v.z = acc[4 * m4 + 2]; v.w = acc[4 * m4 + 3];
        reinterpret_cast<float4*>(ob)[m4] = v;
    }
}

// rare path: exact-sign recompute in fp64 (drow is an LDS row, P column scol)
__device__ __noinline__ float qjl_fixsign(const float* drow, const float* __restrict__ P,
                                          int scol) {
    double s = 0.0;
    for (int d = 0; d < D_; ++d)
        s = fma((double)drow[d], (double)P[(size_t)d * S_ + scol], s);
    return (s > 0.0) ? 1.f : -1.f;
}

// ---------------- kernel B: main ----------------
// grid (N/TN, HK, B), block 256 (4 waves). Wave w owns rows [16w,16w+16) for the
// sign matmul and head g=w for the output phase; lane l owns s in {l,l+64,l+128,l+192}.
// NOTE: no min-waves in launch_bounds — (256,4) clamped VGPR to 64 and spilled 2.6 GB
// to scratch (R2 post-mortem). ~104 VGPR still allows 4 blocks/CU (LDS-limited).
__global__ __launch_bounds__(256) void qjl_main(const float* __restrict__ data,
                                                const float* __restrict__ q,
                                                const float* __restrict__ P,
                                                const int* __restrict__ oidx,
                                                const float* __restrict__ sq,
                                                float* __restrict__ out) {
    __shared__ float sdata[TN][D_];              // 32 KB, outliers zeroed in place
    __shared__ union {                            // 2 KB, phase-disjoint (barrier-separated)
        float svals[TN][O_];                      //   phases A,B: original outlier values
        unsigned long long sbits[TN][4];          //   phases C,D: sign_in bitmasks
    } uo;
    __shared__ int   sidxs[TN][O_];               // dedup'd indices (-1 = dup slot)
    __shared__ float su[TN][O_];                  // u_j per row
    __shared__ float sfull[TN];                   // full row sum-of-squares
    __shared__ float snin[TN];                    // c_in  * ||k_in||
    __shared__ float snout[TN];                   // c_out * ||k_out||

    const int tid = threadIdx.x;
    const int lane = tid & 63;
    const int wv = tid >> 6;
    const int nt = blockIdx.x, hk = blockIdx.y, b = blockIdx.z;
    const int n0 = nt * TN;

    // ---- phase 0: load data tile (+ per-row sumsq) ----
    {
        const int r = tid >> 2;  // row 0..63
        const int c = tid & 3;
        const float* drow = data + ((size_t)(b * HK_ + hk) * N_ + n0 + r) * D_;
        float ssq = 0.f;
#pragma unroll
        for (int k = 0; k < 8; ++k) {
            const int f = c + 4 * k;
            float4 v = reinterpret_cast<const float4*>(drow)[f];
            reinterpret_cast<float4*>(&sdata[r][0])[f] = v;
            ssq += v.x * v.x + v.y * v.y + v.z * v.z + v.w * v.w;
        }
        ssq += __shfl_xor(ssq, 1);
        ssq += __shfl_xor(ssq, 2);
        if (c == 0) sfull[r] = ssq;
    }
    __syncthreads();

    // ---- phase A: dedup outliers, record values, zero them in sdata, norms ----
    if (tid < TN) {
        const int n = tid;
        const int* ob = oidx + ((size_t)(b * HK_ + hk) * N_ + n0 + n) * O_;
        int id[O_];
        int4 i0 = reinterpret_cast<const int4*>(ob)[0];
        int4 i1 = reinterpret_cast<const int4*>(ob)[1];
        id[0] = i0.x; id[1] = i0.y; id[2] = i0.z; id[3] = i0.w;
        id[4] = i1.x; id[5] = i1.y; id[6] = i1.z; id[7] = i1.w;
        float so2 = 0.f;
#pragma unroll
        for (int j = 0; j < O_; ++j) {
            bool dup = false;
#pragma unroll
            for (int jj = 0; jj < O_; ++jj)
                if (jj < j) dup = dup || (id[jj] == id[j]);
            if (!dup) {
                const float v = sdata[n][id[j]];
                uo.svals[n][j] = v;
                sidxs[n][j] = id[j];
                so2 = fmaf(v, v, so2);
                sdata[n][id[j]] = 0.f;  // sdata now holds k_in exactly
            } else {
                uo.svals[n][j] = 0.f;
                sidxs[n][j] = -1;
            }
        }
        const float CIN = (float)(1.2533141373155003 / 256.0);   // sqrt(pi/2)/S
        const float COUT = (float)(1.2533141373155003 / 64.0);   // sqrt(pi/2)/SO
        snin[n] = CIN * sqrtf(fmaxf(sfull[n] - so2, 0.f));
        snout[n] = COUT * sqrtf(so2);
    }
    __syncthreads();

    // ---- phase B: sign_out (fp64 dot) and u_j; 4 threads per row ----
    {
        const int n = tid >> 2;
        const int c = tid & 3;
        float u[O_];
        float vv[O_];
        int idc[O_];
#pragma unroll
        for (int j = 0; j < O_; ++j) {
            u[j] = 0.f;
            const int ix = sidxs[n][j];
            idc[j] = (ix >= 0) ? ix : 0;  // clamp dups; their u is never used
            vv[j] = uo.svals[n][j];       // dups carry 0 -> no effect on cs
        }
        for (int t = c * 16; t < c * 16 + 16; ++t) {
            double cs = 0.0;
#pragma unroll
            for (int j = 0; j < O_; ++j)
                cs = fma((double)vv[j], (double)P[idc[j] * S_ + t], cs);
            const float sg = (cs > 0.0) ? 1.f : ((cs < 0.0) ? -1.f : 0.f);
#pragma unroll
            for (int j = 0; j < O_; ++j)
                u[j] = fmaf(sg, P[idc[j] * S_ + t], u[j]);
        }
#pragma unroll
        for (int j = 0; j < O_; ++j) {
            u[j] += __shfl_xor(u[j], 1);
            u[j] += __shfl_xor(u[j], 2);
        }
        if (c == 0) {
#pragma unroll
            for (int j = 0; j < O_; ++j) su[n][j] = u[j];
        }
    }
    __syncthreads();  // svals reads (B) complete before sbits writes (C); su visible to D

    // ---- phase C: G = k_in · P, fp32 acc + tau-guarded fp64 sign fixup; pack bits ----
    {
        float acc[16][4];
#pragma unroll
        for (int r = 0; r < 16; ++r)
#pragma unroll
            for (int k = 0; k < 4; ++k) acc[r][k] = 0.f;

        const float* Pl = P + lane;  // coalesced: lane l reads columns 64k+l
        for (int dc = 0; dc < D_; dc += 4) {
            const float* Pb = Pl + (size_t)dc * S_;
            float pv[4][4];
#pragma unroll
            for (int i = 0; i < 4; ++i)
#pragma unroll
                for (int k = 0; k < 4; ++k) pv[i][k] = Pb[i * S_ + 64 * k];
#pragma unroll
            for (int r = 0; r < 16; ++r) {
                const float4 dv = *reinterpret_cast<const float4*>(&sdata[wv * 16 + r][dc]);
#pragma unroll
                for (int k = 0; k < 4; ++k) {
                    float a = acc[r][k];
                    a = fmaf(dv.x, pv[0][k], a);
                    a = fmaf(dv.y, pv[1][k], a);
                    a = fmaf(dv.z, pv[2][k], a);
                    a = fmaf(dv.w, pv[3][k], a);
                    acc[r][k] = a;
                }
            }
        }
#pragma unroll
        for (int r = 0; r < 16; ++r) {
            unsigned long long bb[4];
#pragma unroll
            for (int k = 0; k < 4; ++k) {
                float a = acc[r][k];
                if (__ballot(fabsf(a) < TAU) != 0ull) {   // rare: ~2 cells per block
                    if (fabsf(a) < TAU)
                        a = qjl_fixsign(&sdata[wv * 16 + r][0], P, 64 * k + lane);
                }
                bb[k] = __ballot(a > 0.f);
            }
            if (lane == 0) {
#pragma unroll
                for (int k = 0; k < 4; ++k) uo.sbits[wv * 16 + r][k] = bb[k];
            }
        }
    }
    __syncthreads();

    // ---- phase D: part1 (signed sum of sqT via cndmask+fma) + part2 (sparse) + store ----
    {
        const int n = lane;           // row within tile
        const int hq = hk * G_ + wv;  // wave owns one head of the group
        const float* qrow = q + (size_t)(b * HQ_ + hq) * (M_ * D_);
        float accO[M_];
#pragma unroll
        for (int m = 0; m < M_; ++m) accO[m] = 0.f;
        const float cno = snout[n];
#pragma unroll
        for (int j = 0; j < O_; ++j) {
            const int ix = sidxs[n][j];
            const int ixc = (ix >= 0) ? ix : 0;
            const float uj = (ix >= 0) ? su[n][j] * cno : 0.f;
#pragma unroll
            for (int m = 0; m < M_; ++m)
                accO[m] = fmaf(uj, qrow[m * D_ + ixc], accO[m]);
        }

        unsigned long long bw[4];
#pragma unroll
        for (int k = 0; k < 4; ++k) bw[k] = uo.sbits[n][k];

        // force the sq base scalar so the broadcast reads become s_load
        const int head = __builtin_amdgcn_readfirstlane(b * HQ_ + hq);
        const float* sqb = sq + (size_t)head * (M_ * S_);  // [s][m] layout
        float accI[M_];
#pragma unroll
        for (int m = 0; m < M_; ++m) accI[m] = 0.f;
        for (int k = 0; k < 4; ++k) {
            const unsigned long long w64 = bw[k];
            const float* sb_base = sqb + (size_t)k * 64 * M_;
            for (int sb = 0; sb < 64; ++sb) {
                // sgn = +1 if bit set, else -1; fma(sgn,v,acc) == acc ± v exactly
                const float sgn = ((w64 >> sb) & 1ull) ? 1.f : -1.f;
                const float4* sp = reinterpret_cast<const float4*>(sb_base + sb * M_);
                const float4 v0 = sp[0], v1 = sp[1], v2 = sp[2], v3 = sp[3];
                accI[0]  = fmaf(sgn, v0.x, accI[0]);
                accI[1]  = fmaf(sgn, v0.y, accI[1]);
                accI[2]  = fmaf(sgn, v0.z, accI[2]);
                accI[3]  = fmaf(sgn, v0.w, accI[3]);
                accI[4]  = fmaf(sgn, v1.x, accI[4]);
                accI[5]  = fmaf(sgn, v1.y, accI[5]);
                accI[6]  = fmaf(sgn, v1.z, accI[6]);
                accI[7]  = fmaf(sgn, v1.w, accI[7]);
                accI[8]  = fmaf(sgn, v2.x, accI[8]);
                accI[9]  = fmaf(sgn, v2.y, accI[9]);
                accI[10] = fmaf(sgn, v2.z, accI[10]);
                accI[11] = fmaf(sgn, v2.w, accI[11]);
                accI[12] = fmaf(sgn, v3.x, accI[12]);
                accI[13] = fmaf(sgn, v3.y, accI[13]);
                accI[14] = fmaf(sgn, v3.z, accI[14]);
                accI[15] = fmaf(sgn, v3.w, accI[15]);
            }
        }

        const float cni = snin[n];
        float* ob = out + ((size_t)(b * HQ_ + hq) * N_ + (n0 + n)) * M_;
#pragma unroll
        for (int m4 = 0; m4 < M_ / 4; ++m4) {
            float4 v;
            v.x = fmaf(accI[4 * m4 + 0], cni, accO[4 * m4 + 0]);
            v.y = fmaf(accI[4 * m4 + 1], cni, accO[4 * m4 + 1]);
            v.z = fmaf(accI[4 * m4 + 2], cni, accO[4 * m4 + 2]);
            v.w = fmaf(accI[4 * m4 + 3], cni, accO[4 * m4 + 3]);
            reinterpret_cast<float4*>(ob)[m4] = v;
        }
    }
}

extern "C" void kernel_launch(void* const* d_in, const int* in_sizes, int n_in,
                              void* d_out, int out_size, void* d_ws, size_t ws_size,
                              hipStream_t stream) {
    const float* query = (const float*)d_in[0];  // [B][HQ][M][D]
    const float* data  = (const float*)d_in[1];  // [B][HK][N][D]
    const float* proj  = (const float*)d_in[2];  // [D][S]
    const int*   oidx  = (const int*)d_in[3];    // [B][HK][N][O]
    // d_in[4] = dim_outlier scalar (=64), baked in as SO

    float* out = (float*)d_out;                  // [B][HQ][N][M]
    float* sq = (float*)d_ws;                    // B*HQ*S*M floats = 2 MB scratch (transposed)

    qjl_sketch_q<<<dim3(B_ * HQ_), dim3(256), 0, stream>>>(query, proj, sq);
    qjl_main<<<dim3(N_ / TN, HK_, B_), dim3(256), 0, stream>>>(data, query, proj, oidx, sq, out);
}

// Round 4
// 443.741 us; speedup vs baseline: 3.3858x; 1.4267x over previous
//
#include <hip/hip_runtime.h>
#include <hip/hip_bf16.h>
#include <math.h>

namespace {
constexpr int B_ = 4, HQ_ = 32, HK_ = 8, G_ = 4, M_ = 16;
constexpr int N_ = 8192, D_ = 128, S_ = 256, O_ = 8;
constexpr int TN = 64;               // n-rows per block
constexpr float TAU = 4e-3f;         // |dot| below this -> exact fp64 sign recheck
}

typedef short short8 __attribute__((ext_vector_type(8)));
typedef float f32x4 __attribute__((ext_vector_type(4)));
typedef unsigned int uint4_ __attribute__((ext_vector_type(4)));

__device__ inline unsigned short f2bf_rne(float f) {
    unsigned u = __float_as_uint(f);
    u += 0x7FFF + ((u >> 16) & 1);
    return (unsigned short)(u >> 16);
}
__device__ inline float bf2f(unsigned short h) {
    return __uint_as_float(((unsigned)h) << 16);
}

// ---------------- kernel P-split: PtHi/PtLo[s][d] = bf16 hi/lo of P[d][s] ----------------
__global__ __launch_bounds__(256) void qjl_prept(const float* __restrict__ P,
                                                 unsigned short* __restrict__ PtHi,
                                                 unsigned short* __restrict__ PtLo) {
    const int d = blockIdx.x;      // 0..127
    const int s = threadIdx.x;     // 0..255
    const float f = P[d * S_ + s];
    const unsigned short hb = f2bf_rne(f);
    const float lof = f - bf2f(hb);
    PtHi[s * D_ + d] = hb;
    PtLo[s * D_ + d] = f2bf_rne(lof);
}

// ---------------- kernel A: sqHi[head][m][s] = bf16(q · P) ----------------
__global__ __launch_bounds__(256) void qjl_sketch_q(const float* __restrict__ q,
                                                    const float* __restrict__ P,
                                                    unsigned short* __restrict__ sqHi) {
    __shared__ float qs[M_][D_];
    const int tid = threadIdx.x;
    const size_t blk = blockIdx.x;  // b*HQ + hq
    const float* qb = q + blk * (size_t)(M_ * D_);
    for (int i = tid; i < M_ * D_ / 4; i += 256)
        reinterpret_cast<float4*>(&qs[0][0])[i] = reinterpret_cast<const float4*>(qb)[i];
    __syncthreads();
    float acc[M_];
#pragma unroll
    for (int m = 0; m < M_; ++m) acc[m] = 0.f;
    const int s = tid;
    for (int d = 0; d < D_; ++d) {
        const float pv = P[d * S_ + s];
#pragma unroll
        for (int m = 0; m < M_; ++m) acc[m] = fmaf(qs[m][d], pv, acc[m]);
    }
    unsigned short* ob = sqHi + blk * (size_t)(M_ * S_);
#pragma unroll
    for (int m = 0; m < M_; ++m) ob[m * S_ + s] = f2bf_rne(acc[m]);
}

// rare cooperative path: exact fp64 sign of k_in[row] . P[:,col]; all 64 lanes participate
__device__ __noinline__ float qjl_fix_coop(const float* __restrict__ drow,
                                           const float* __restrict__ P,
                                           int col, unsigned long long ip,
                                           float a, int src) {
    const int lane = threadIdx.x & 63;
    double p = 0.0;
#pragma unroll
    for (int e = 0; e < 2; ++e) {
        const int d = 2 * lane + e;
        const float v = drow[d];
        bool isout = false;
#pragma unroll
        for (int j = 0; j < 8; ++j)
            isout = isout || (((unsigned)(ip >> (8 * j)) & 0xFFu) == (unsigned)d);
        if (!isout) p = fma((double)v, (double)P[(size_t)d * S_ + col], p);
    }
#pragma unroll
    for (int off = 1; off < 64; off <<= 1) p += __shfl_xor(p, off);
    if (lane == src) a = (p > 0.0) ? 1.f : -1.f;
    return a;
}

// ---------------- kernel B: main ----------------
// grid (N/TN, HK, B), block 256 (4 waves). Wave wv: sign-matmul rows [16wv,16wv+16),
// output head hq = hk*G + wv.
__global__ __launch_bounds__(256) void qjl_main(const float* __restrict__ data,
                                                const float* __restrict__ q,
                                                const float* __restrict__ P,
                                                const int* __restrict__ oidx,
                                                const unsigned short* __restrict__ sqHi,
                                                const unsigned short* __restrict__ PtHi,
                                                const unsigned short* __restrict__ PtLo,
                                                float* __restrict__ out) {
    // abuf: phases 0..C: hi = [0..8191], lo = [8192..16383]  (elem idx row*128+d, XOR-swz)
    //       phases expand..D: scol[64][256] bf16 = +/- cni[n]  (elem idx n*256+s, XOR-swz)
    __shared__ unsigned short abuf[16384];                 // 32 KB (phase-disjoint union)
    __shared__ unsigned long long words[4][16][4];         // 2 KB ballot words
    __shared__ float su2[TN][O_];                          // sign_out-weighted u (pre-scaled)
    __shared__ unsigned long long sidxp[TN];               // 8 outlier idx bytes (0xFF = dup)
    __shared__ float sfull[TN];
    __shared__ float snin[TN];                             // c_in * ||k_in||
    __shared__ float snout[TN];                            // c_out * ||k_out||

    const int tid = threadIdx.x;
    const int lane = tid & 63;
    const int wv = tid >> 6;
    const int nt = blockIdx.x, hk = blockIdx.y, b = blockIdx.z;
    const int n0 = nt * TN;
    const float* dbase = data + ((size_t)(b * HK_ + hk) * N_) * D_;

    // ---- phase 0: load data tile, bf16 hi/lo split into LDS, per-row sumsq ----
    {
        const int r = tid >> 2;   // row 0..63
        const int c = tid & 3;
        const float* drow = dbase + (size_t)(n0 + r) * D_;
        const int swz = (r & 7) << 3;
        float ssq = 0.f;
#pragma unroll
        for (int k = 0; k < 8; ++k) {
            const int f = c + 4 * k;          // float4 index; elems d = 4f..4f+3
            float4 v = reinterpret_cast<const float4*>(drow)[f];
            ssq += v.x * v.x + v.y * v.y + v.z * v.z + v.w * v.w;
            unsigned short h0 = f2bf_rne(v.x), h1 = f2bf_rne(v.y),
                           h2 = f2bf_rne(v.z), h3 = f2bf_rne(v.w);
            unsigned short l0 = f2bf_rne(v.x - bf2f(h0)), l1 = f2bf_rne(v.y - bf2f(h1)),
                           l2 = f2bf_rne(v.z - bf2f(h2)), l3 = f2bf_rne(v.w - bf2f(h3));
            const int ei = r * 128 + ((4 * f) ^ swz);
            unsigned long long hw = (unsigned long long)h0 | ((unsigned long long)h1 << 16) |
                                    ((unsigned long long)h2 << 32) | ((unsigned long long)h3 << 48);
            unsigned long long lw = (unsigned long long)l0 | ((unsigned long long)l1 << 16) |
                                    ((unsigned long long)l2 << 32) | ((unsigned long long)l3 << 48);
            *reinterpret_cast<unsigned long long*>(&abuf[ei]) = hw;
            *reinterpret_cast<unsigned long long*>(&abuf[8192 + ei]) = lw;
        }
        ssq += __shfl_xor(ssq, 1);
        ssq += __shfl_xor(ssq, 2);
        if (c == 0) sfull[r] = ssq;
    }
    __syncthreads();

    // ---- phase A: dedup outliers (exact values from global), zero them in LDS, norms ----
    if (tid < TN) {
        const int n = tid;
        const int* ob = oidx + ((size_t)(b * HK_ + hk) * N_ + n0 + n) * O_;
        const float* drow = dbase + (size_t)(n0 + n) * D_;
        int id[O_];
        int4 i0 = reinterpret_cast<const int4*>(ob)[0];
        int4 i1 = reinterpret_cast<const int4*>(ob)[1];
        id[0] = i0.x; id[1] = i0.y; id[2] = i0.z; id[3] = i0.w;
        id[4] = i1.x; id[5] = i1.y; id[6] = i1.z; id[7] = i1.w;
        const int swz = (n & 7) << 3;
        unsigned long long ip = 0;
        float so2 = 0.f;
#pragma unroll
        for (int j = 0; j < O_; ++j) {
            bool dup = false;
#pragma unroll
            for (int jj = 0; jj < O_; ++jj)
                if (jj < j) dup = dup || (id[jj] == id[j]);
            if (!dup) {
                const float v = drow[id[j]];
                so2 = fmaf(v, v, so2);
                ip |= (unsigned long long)(id[j] & 0xFF) << (8 * j);
                const int ei = n * 128 + (id[j] ^ swz);
                abuf[ei] = 0;          // hi = 0
                abuf[8192 + ei] = 0;   // lo = 0  -> k_in exactly
            } else {
                ip |= 0xFFull << (8 * j);
            }
        }
        sidxp[n] = ip;
        const float CIN = (float)(1.2533141373155003 / 256.0);
        const float COUT = (float)(1.2533141373155003 / 64.0);
        snin[n] = CIN * sqrtf(fmaxf(sfull[n] - so2, 0.f));
        snout[n] = COUT * sqrtf(so2);
    }
    __syncthreads();

    // ---- phase B: sign_out (fp64, exact values from global) -> su2 = u * cout*normout ----
    {
        const int n = tid >> 2;
        const int c = tid & 3;
        const unsigned long long ip = sidxp[n];
        const float* drow = dbase + (size_t)(n0 + n) * D_;
        float u[O_];
        float vv[O_];
        int idc[O_];
        bool val[O_];
#pragma unroll
        for (int j = 0; j < O_; ++j) {
            u[j] = 0.f;
            const unsigned bt = (unsigned)(ip >> (8 * j)) & 0xFFu;
            val[j] = (bt != 0xFFu);
            idc[j] = (int)(bt & 0x7Fu);
            vv[j] = val[j] ? drow[idc[j]] : 0.f;
        }
        for (int t = c * 16; t < c * 16 + 16; ++t) {
            double cs = 0.0;
#pragma unroll
            for (int j = 0; j < O_; ++j)
                cs = fma((double)vv[j], (double)P[idc[j] * S_ + t], cs);
            const float sg = (cs > 0.0) ? 1.f : ((cs < 0.0) ? -1.f : 0.f);
#pragma unroll
            for (int j = 0; j < O_; ++j)
                u[j] = fmaf(sg, P[idc[j] * S_ + t], u[j]);
        }
#pragma unroll
        for (int j = 0; j < O_; ++j) {
            u[j] += __shfl_xor(u[j], 1);
            u[j] += __shfl_xor(u[j], 2);
        }
        if (c == 0) {
            const float cno = snout[n];
#pragma unroll
            for (int j = 0; j < O_; ++j) su2[n][j] = val[j] ? u[j] * cno : 0.f;
        }
    }
    __syncthreads();

    // ---- phase C: signs = sgn(k_in . P) via bf16 hi/lo MFMA + tau-guarded exact fixup ----
    {
        const int arow = 16 * wv + (lane & 15);
        const int aswz = (arow & 7) << 3;
        const int kgrp = (lane >> 4) << 3;
#pragma unroll
        for (int half = 0; half < 2; ++half) {
            short8 ahi[4], alo[4];
#pragma unroll
            for (int ks = 0; ks < 4; ++ks) {
                const int ei = arow * 128 + ((ks * 32 + kgrp) ^ aswz);
                ahi[ks] = *reinterpret_cast<const short8*>(&abuf[ei]);
                alo[ks] = *reinterpret_cast<const short8*>(&abuf[8192 + ei]);
            }
            f32x4 acc[8];
#pragma unroll
            for (int t8 = 0; t8 < 8; ++t8) {
                acc[t8] = (f32x4){0.f, 0.f, 0.f, 0.f};
                const int t = half * 8 + t8;
                const size_t bo = (size_t)(16 * t + (lane & 15)) * D_ + kgrp;
#pragma unroll
                for (int ks = 0; ks < 4; ++ks) {
                    const short8 bhi = *reinterpret_cast<const short8*>(PtHi + bo + ks * 32);
                    const short8 blo = *reinterpret_cast<const short8*>(PtLo + bo + ks * 32);
                    acc[t8] = __builtin_amdgcn_mfma_f32_16x16x32_bf16(ahi[ks], bhi, acc[t8], 0, 0, 0);
                    acc[t8] = __builtin_amdgcn_mfma_f32_16x16x32_bf16(ahi[ks], blo, acc[t8], 0, 0, 0);
                    acc[t8] = __builtin_amdgcn_mfma_f32_16x16x32_bf16(alo[ks], bhi, acc[t8], 0, 0, 0);
                }
            }
            // ballots (+ rare exact fixup), store raw words
#pragma unroll
            for (int t8 = 0; t8 < 8; ++t8) {
                const int t = half * 8 + t8;
#pragma unroll
                for (int r = 0; r < 4; ++r) {
                    float a = acc[t8][r];
                    unsigned long long low = __ballot(fabsf(a) < TAU);
                    while (low) {
                        const int src = __ffsll((unsigned long long)low) - 1;
                        low &= low - 1;
                        const int row = 16 * wv + ((src >> 4) << 2) + r;
                        const int col = 16 * t + (src & 15);
                        a = qjl_fix_coop(dbase + (size_t)(n0 + row) * D_, P, col,
                                         sidxp[row], a, src);
                    }
                    const unsigned long long bb = __ballot(a > 0.f);
                    if (lane == 0) words[wv][t][r] = bb;
                }
            }
        }
    }
    __syncthreads();

    // ---- expansion: scol[n][s] = (sign ? +1 : -1) * bf16(cni[n]), overwrites abuf ----
    {
        const int n = tid & 63;
        const int c64 = tid >> 6;
        const unsigned short cb = f2bf_rne(snin[n]);
        const unsigned base = (unsigned)cb | ((unsigned)cb << 16);
        const int g = (n >> 2) & 3;
        const int r = n & 3;
        const int w = n >> 4;
        const int swz = (n & 7) << 3;
#pragma unroll
        for (int i = 0; i < 4; ++i) {
            const int t = c64 * 4 + i;
            const unsigned long long wd = words[w][t][r];
            const unsigned bits = (unsigned)(wd >> (16 * g)) & 0xFFFFu;
            const unsigned nb = ~bits;
            unsigned o[8];
#pragma unroll
            for (int p = 0; p < 8; ++p) {
                const unsigned m = (((nb >> (2 * p)) & 1u) << 15) |
                                   (((nb >> (2 * p + 1)) & 1u) << 31);
                o[p] = base ^ m;
            }
            const int s0 = c64 * 64 + i * 16;
            const int e0 = n * 256 + (s0 ^ swz);
            const int e1 = n * 256 + ((s0 + 8) ^ swz);
            *reinterpret_cast<uint4_*>(&abuf[e0]) = (uint4_){o[0], o[1], o[2], o[3]};
            *reinterpret_cast<uint4_*>(&abuf[e1]) = (uint4_){o[4], o[5], o[6], o[7]};
        }
    }
    __syncthreads();

    // ---- phase D: out[n][m] = part2 + MFMA(sq_bf16, scol) ----
    {
        const int hq = hk * G_ + wv;
        const unsigned short* sqb = sqHi + (size_t)(b * HQ_ + hq) * (M_ * S_);
        const float* qhead = q + (size_t)(b * HQ_ + hq) * (M_ * D_);
        const int kgrp = (lane >> 4) << 3;
        const int m0 = (lane >> 4) << 2;
        short8 aq[8];
#pragma unroll
        for (int ks = 0; ks < 8; ++ks)
            aq[ks] = *reinterpret_cast<const short8*>(sqb + (size_t)(lane & 15) * S_ + ks * 32 + kgrp);

#pragma unroll
        for (int ct = 0; ct < 4; ++ct) {
            const int n = 16 * ct + (lane & 15);
            // part2 init (sparse outlier dot)
            const f32x4 s01 = *reinterpret_cast<const f32x4*>(&su2[n][0]);
            const f32x4 s23 = *reinterpret_cast<const f32x4*>(&su2[n][4]);
            const unsigned long long ip = sidxp[n];
            float a0 = 0.f, a1 = 0.f, a2 = 0.f, a3 = 0.f;
#pragma unroll
            for (int j = 0; j < O_; ++j) {
                const float uj = (j < 4) ? s01[j & 3] : s23[j & 3];
                const int ix = (int)((ip >> (8 * j)) & 0x7Fu);
                const float* qp = qhead + ix;
                a0 = fmaf(uj, qp[(m0 + 0) * D_], a0);
                a1 = fmaf(uj, qp[(m0 + 1) * D_], a1);
                a2 = fmaf(uj, qp[(m0 + 2) * D_], a2);
                a3 = fmaf(uj, qp[(m0 + 3) * D_], a3);
            }
            f32x4 acc = (f32x4){a0, a1, a2, a3};
            // part1 via MFMA over S=256
            const int nswz = (n & 7) << 3;
#pragma unroll
            for (int ks = 0; ks < 8; ++ks) {
                const int ei = n * 256 + ((ks * 32 + kgrp) ^ nswz);
                const short8 bs = *reinterpret_cast<const short8*>(&abuf[ei]);
                acc = __builtin_amdgcn_mfma_f32_16x16x32_bf16(aq[ks], bs, acc, 0, 0, 0);
            }
            float* ob = out + ((size_t)(b * HQ_ + hq) * N_ + (n0 + n)) * M_ + m0;
            *reinterpret_cast<f32x4*>(ob) = acc;
        }
    }
}

extern "C" void kernel_launch(void* const* d_in, const int* in_sizes, int n_in,
                              void* d_out, int out_size, void* d_ws, size_t ws_size,
                              hipStream_t stream) {
    const float* query = (const float*)d_in[0];  // [B][HQ][M][D]
    const float* data  = (const float*)d_in[1];  // [B][HK][N][D]
    const float* proj  = (const float*)d_in[2];  // [D][S]
    const int*   oidx  = (const int*)d_in[3];    // [B][HK][N][O]

    float* out = (float*)d_out;                  // [B][HQ][N][M]
    unsigned short* sqHi = (unsigned short*)d_ws;                         // 1 MB
    unsigned short* PtHi = (unsigned short*)((char*)d_ws + (1 << 20));    // 64 KB
    unsigned short* PtLo = (unsigned short*)((char*)d_ws + (1 << 20) + (64 << 10));

    qjl_prept<<<dim3(D_), dim3(S_), 0, stream>>>(proj, PtHi, PtLo);
    qjl_sketch_q<<<dim3(B_ * HQ_), dim3(256), 0, stream>>>(query, proj, sqHi);
    qjl_main<<<dim3(N_ / TN, HK_, B_), dim3(256), 0, stream>>>(data, query, proj, oidx,
                                                               sqHi, PtHi, PtLo, out);
}

// Round 5
// 254.452 us; speedup vs baseline: 5.9045x; 1.7439x over previous
//
#include <hip/hip_runtime.h>
#include <hip/hip_bf16.h>
#include <math.h>

namespace {
constexpr int B_ = 4, HQ_ = 32, HK_ = 8, G_ = 4, M_ = 16;
constexpr int N_ = 8192, D_ = 128, S_ = 256, O_ = 8;
constexpr int TN = 64;               // n-rows per block
constexpr float TAU = 4e-3f;         // |dot| below this -> exact fp64 sign recheck
}

typedef short short8 __attribute__((ext_vector_type(8)));
typedef float f32x4 __attribute__((ext_vector_type(4)));
typedef unsigned int uint4_ __attribute__((ext_vector_type(4)));

__device__ inline unsigned short f2bf_rne(float f) {
    unsigned u = __float_as_uint(f);
    u += 0x7FFF + ((u >> 16) & 1);
    return (unsigned short)(u >> 16);
}
__device__ inline float bf2f(unsigned short h) {
    return __uint_as_float(((unsigned)h) << 16);
}

// ---------------- kernel P-split: PtHi/PtLo[s][d] = bf16 hi/lo of P[d][s]; Pt32 fp32 ----
__global__ __launch_bounds__(256) void qjl_prept(const float* __restrict__ P,
                                                 unsigned short* __restrict__ PtHi,
                                                 unsigned short* __restrict__ PtLo,
                                                 float* __restrict__ Pt32) {
    const int d = blockIdx.x;      // 0..127
    const int s = threadIdx.x;     // 0..255
    const float f = P[d * S_ + s];
    const unsigned short hb = f2bf_rne(f);
    const float lof = f - bf2f(hb);
    PtHi[s * D_ + d] = hb;
    PtLo[s * D_ + d] = f2bf_rne(lof);
    Pt32[s * D_ + d] = f;
}

// ---------------- kernel A: sqHi[head][m][s] = bf16(q · P) ----------------
__global__ __launch_bounds__(256) void qjl_sketch_q(const float* __restrict__ q,
                                                    const float* __restrict__ P,
                                                    unsigned short* __restrict__ sqHi) {
    __shared__ float qs[M_][D_];
    const int tid = threadIdx.x;
    const size_t blk = blockIdx.x;  // b*HQ + hq
    const float* qb = q + blk * (size_t)(M_ * D_);
    for (int i = tid; i < M_ * D_ / 4; i += 256)
        reinterpret_cast<float4*>(&qs[0][0])[i] = reinterpret_cast<const float4*>(qb)[i];
    __syncthreads();
    float acc[M_];
#pragma unroll
    for (int m = 0; m < M_; ++m) acc[m] = 0.f;
    const int s = tid;
    for (int d = 0; d < D_; ++d) {
        const float pv = P[d * S_ + s];
#pragma unroll
        for (int m = 0; m < M_; ++m) acc[m] = fmaf(qs[m][d], pv, acc[m]);
    }
    unsigned short* ob = sqHi + blk * (size_t)(M_ * S_);
#pragma unroll
    for (int m = 0; m < M_; ++m) ob[m * S_ + s] = f2bf_rne(acc[m]);
}

// rare cooperative path: exact fp64 sign of k_in[row] . P[:,col]; all 64 lanes participate.
// Pt32 is fp32 P transposed [s][d] -> contiguous float2 per lane (no column gather).
__device__ __noinline__ float qjl_fix_coop(const float* __restrict__ drow,
                                           const float* __restrict__ Pt32,
                                           int col, unsigned long long ip,
                                           float a, int src) {
    const int lane = threadIdx.x & 63;
    const float2 dv = *reinterpret_cast<const float2*>(&drow[2 * lane]);
    const float2 pv = *reinterpret_cast<const float2*>(&Pt32[(size_t)col * D_ + 2 * lane]);
    double p = 0.0;
#pragma unroll
    for (int e = 0; e < 2; ++e) {
        const int d = 2 * lane + e;
        const float v = e ? dv.y : dv.x;
        const float pw = e ? pv.y : pv.x;
        bool isout = false;
#pragma unroll
        for (int j = 0; j < 8; ++j)
            isout = isout || (((unsigned)(ip >> (8 * j)) & 0xFFu) == (unsigned)d);
        if (!isout) p = fma((double)v, (double)pw, p);
    }
#pragma unroll
    for (int off = 1; off < 64; off <<= 1) p += __shfl_xor(p, off);
    if (lane == src) a = (p > 0.0) ? 1.f : -1.f;
    return a;
}

// ---------------- kernel B: main ----------------
// grid (N/TN, HK, B), block 256 (4 waves).
// Phase C: wave wv owns ALL 64 rows x cols [64wv, 64wv+64) (t-tiles 4wv..4wv+3),
//          B double-buffered in regs (32 global loads/wave; block reads Pt exactly once).
// Phase D: wave wv owns head hq = hk*G + wv.
__global__ __launch_bounds__(256) void qjl_main(const float* __restrict__ data,
                                                const float* __restrict__ q,
                                                const float* __restrict__ P,
                                                const int* __restrict__ oidx,
                                                const unsigned short* __restrict__ sqHi,
                                                const unsigned short* __restrict__ PtHi,
                                                const unsigned short* __restrict__ PtLo,
                                                const float* __restrict__ Pt32,
                                                float* __restrict__ out) {
    // abuf: phases 0..C: hi = [0..8191], lo = [8192..16383]  (elem idx row*128+d, XOR-swz)
    //       phases expand..D: scol[64][256] bf16 = +/- cni[n]  (elem idx n*256+s, XOR-swz)
    __shared__ unsigned short abuf[16384];                 // 32 KB (phase-disjoint union)
    __shared__ unsigned long long words[4][16][4];         // 2 KB; [rowtile][t][r]
    __shared__ float su2[TN][O_];                          // sign_out-weighted u (pre-scaled)
    __shared__ unsigned long long sidxp[TN];               // 8 outlier idx bytes (0xFF = dup)
    __shared__ float sfull[TN];
    __shared__ float snin[TN];                             // c_in * ||k_in||
    __shared__ float snout[TN];                            // c_out * ||k_out||

    const int tid = threadIdx.x;
    const int lane = tid & 63;
    const int wv = tid >> 6;
    const int l15 = lane & 15;
    const int kgrp = (lane >> 4) << 3;
    const int nt = blockIdx.x, hk = blockIdx.y, b = blockIdx.z;
    const int n0 = nt * TN;
    const float* dbase = data + ((size_t)(b * HK_ + hk) * N_) * D_;

    // ---- phase 0: load data tile, bf16 hi/lo split into LDS, per-row sumsq ----
    {
        const int r = tid >> 2;   // row 0..63
        const int c = tid & 3;
        const float* drow = dbase + (size_t)(n0 + r) * D_;
        const int swz = (r & 7) << 3;
        float ssq = 0.f;
#pragma unroll
        for (int k = 0; k < 8; ++k) {
            const int f = c + 4 * k;          // float4 index; elems d = 4f..4f+3
            float4 v = reinterpret_cast<const float4*>(drow)[f];
            ssq += v.x * v.x + v.y * v.y + v.z * v.z + v.w * v.w;
            unsigned short h0 = f2bf_rne(v.x), h1 = f2bf_rne(v.y),
                           h2 = f2bf_rne(v.z), h3 = f2bf_rne(v.w);
            unsigned short l0 = f2bf_rne(v.x - bf2f(h0)), l1 = f2bf_rne(v.y - bf2f(h1)),
                           l2 = f2bf_rne(v.z - bf2f(h2)), l3 = f2bf_rne(v.w - bf2f(h3));
            const int ei = r * 128 + ((4 * f) ^ swz);
            unsigned long long hw = (unsigned long long)h0 | ((unsigned long long)h1 << 16) |
                                    ((unsigned long long)h2 << 32) | ((unsigned long long)h3 << 48);
            unsigned long long lw = (unsigned long long)l0 | ((unsigned long long)l1 << 16) |
                                    ((unsigned long long)l2 << 32) | ((unsigned long long)l3 << 48);
            *reinterpret_cast<unsigned long long*>(&abuf[ei]) = hw;
            *reinterpret_cast<unsigned long long*>(&abuf[8192 + ei]) = lw;
        }
        ssq += __shfl_xor(ssq, 1);
        ssq += __shfl_xor(ssq, 2);
        if (c == 0) sfull[r] = ssq;
    }
    __syncthreads();

    // ---- phase A: dedup outliers (exact values from global), zero them in LDS, norms ----
    if (tid < TN) {
        const int n = tid;
        const int* ob = oidx + ((size_t)(b * HK_ + hk) * N_ + n0 + n) * O_;
        const float* drow = dbase + (size_t)(n0 + n) * D_;
        int id[O_];
        int4 i0 = reinterpret_cast<const int4*>(ob)[0];
        int4 i1 = reinterpret_cast<const int4*>(ob)[1];
        id[0] = i0.x; id[1] = i0.y; id[2] = i0.z; id[3] = i0.w;
        id[4] = i1.x; id[5] = i1.y; id[6] = i1.z; id[7] = i1.w;
        const int swz = (n & 7) << 3;
        unsigned long long ip = 0;
        float so2 = 0.f;
#pragma unroll
        for (int j = 0; j < O_; ++j) {
            bool dup = false;
#pragma unroll
            for (int jj = 0; jj < O_; ++jj)
                if (jj < j) dup = dup || (id[jj] == id[j]);
            if (!dup) {
                const float v = drow[id[j]];
                so2 = fmaf(v, v, so2);
                ip |= (unsigned long long)(id[j] & 0xFF) << (8 * j);
                const int ei = n * 128 + (id[j] ^ swz);
                abuf[ei] = 0;          // hi = 0
                abuf[8192 + ei] = 0;   // lo = 0  -> k_in exactly
            } else {
                ip |= 0xFFull << (8 * j);
            }
        }
        sidxp[n] = ip;
        const float CIN = (float)(1.2533141373155003 / 256.0);
        const float COUT = (float)(1.2533141373155003 / 64.0);
        snin[n] = CIN * sqrtf(fmaxf(sfull[n] - so2, 0.f));
        snout[n] = COUT * sqrtf(so2);
    }
    __syncthreads();

    // ---- phase B: sign_out (fp64, exact values) -> su2 = u * cout*normout ----
    {
        const int n = tid >> 2;
        const int c = tid & 3;
        const unsigned long long ip = sidxp[n];
        const float* drow = dbase + (size_t)(n0 + n) * D_;
        float u[O_], vv[O_];
        const float* pr[O_];
        bool val[O_];
#pragma unroll
        for (int j = 0; j < O_; ++j) {
            u[j] = 0.f;
            const unsigned bt = (unsigned)(ip >> (8 * j)) & 0xFFu;
            val[j] = (bt != 0xFFu);
            const int ix = (int)(bt & 0x7Fu);
            pr[j] = P + ix * S_;
            vv[j] = val[j] ? drow[ix] : 0.f;
        }
#pragma unroll
        for (int ch = 0; ch < 4; ++ch) {
            const int tc = c * 16 + ch * 4;
            float4 pj[O_];
#pragma unroll
            for (int j = 0; j < O_; ++j)
                pj[j] = *reinterpret_cast<const float4*>(pr[j] + tc);
#pragma unroll
            for (int e = 0; e < 4; ++e) {
                double cs = 0.0;
#pragma unroll
                for (int j = 0; j < O_; ++j)
                    cs = fma((double)vv[j], (double)pj[j][e], cs);
                const float sg = (cs > 0.0) ? 1.f : ((cs < 0.0) ? -1.f : 0.f);
#pragma unroll
                for (int j = 0; j < O_; ++j)
                    u[j] = fmaf(sg, pj[j][e], u[j]);
            }
        }
#pragma unroll
        for (int j = 0; j < O_; ++j) {
            u[j] += __shfl_xor(u[j], 1);
            u[j] += __shfl_xor(u[j], 2);
        }
        if (c == 0) {
            const float cno = snout[n];
#pragma unroll
            for (int j = 0; j < O_; ++j) su2[n][j] = val[j] ? u[j] * cno : 0.f;
        }
    }

    // ---- phase C B-prefetch (global-only; barrier + first ds reads hide latency) ----
    short8 bhi[2][4], blo[2][4];
    const int t0 = wv * 4;
#define QJL_LOADB(buf, ti)                                                         \
    do {                                                                           \
        const size_t bo = (size_t)(16 * (t0 + (ti)) + l15) * D_ + kgrp;            \
        _Pragma("unroll") for (int ks = 0; ks < 4; ++ks) {                         \
            bhi[buf][ks] = *reinterpret_cast<const short8*>(PtHi + bo + ks * 32);  \
            blo[buf][ks] = *reinterpret_cast<const short8*>(PtLo + bo + ks * 32);  \
        }                                                                          \
    } while (0)
    QJL_LOADB(0, 0);
    __syncthreads();  // phase B's svals/su2 writes visible; abuf stable for C

    // ---- phase C: signs = sgn(k_in . P) via bf16 hi/lo MFMA, wave owns 64 cols ----
    {
#pragma unroll
        for (int ti = 0; ti < 4; ++ti) {
            if (ti < 3) {
                if ((ti & 1) == 0) QJL_LOADB(1, ti + 1);
                else               QJL_LOADB(0, ti + 1);
            }
            const int cur = ti & 1;
            const int t = t0 + ti;
#pragma unroll
            for (int rt = 0; rt < 4; ++rt) {
                const int arow = 16 * rt + l15;
                const int aswz = (arow & 7) << 3;
                short8 ahi[4], alo[4];
#pragma unroll
                for (int ks = 0; ks < 4; ++ks) {
                    const int ei = arow * 128 + ((ks * 32 + kgrp) ^ aswz);
                    ahi[ks] = *reinterpret_cast<const short8*>(&abuf[ei]);
                    alo[ks] = *reinterpret_cast<const short8*>(&abuf[8192 + ei]);
                }
                f32x4 acc = (f32x4){0.f, 0.f, 0.f, 0.f};
#pragma unroll
                for (int ks = 0; ks < 4; ++ks) {
                    acc = __builtin_amdgcn_mfma_f32_16x16x32_bf16(ahi[ks], bhi[cur][ks], acc, 0, 0, 0);
                    acc = __builtin_amdgcn_mfma_f32_16x16x32_bf16(ahi[ks], blo[cur][ks], acc, 0, 0, 0);
                    acc = __builtin_amdgcn_mfma_f32_16x16x32_bf16(alo[ks], bhi[cur][ks], acc, 0, 0, 0);
                }
#pragma unroll
                for (int r = 0; r < 4; ++r) {
                    float a = acc[r];
                    unsigned long long low = __ballot(fabsf(a) < TAU);
                    while (low) {
                        const int src = __ffsll((unsigned long long)low) - 1;
                        low &= low - 1;
                        const int row = 16 * rt + ((src >> 4) << 2) + r;
                        const int col = 16 * t + (src & 15);
                        a = qjl_fix_coop(dbase + (size_t)(n0 + row) * D_, Pt32, col,
                                         sidxp[row], a, src);
                    }
                    const unsigned long long bb = __ballot(a > 0.f);
                    if (lane == 0) words[rt][t][r] = bb;
                }
            }
        }
    }
#undef QJL_LOADB

    // ---- phase D A-prefetch (global-only; expansion phase hides latency) ----
    const int hq = hk * G_ + wv;
    const unsigned short* sqb = sqHi + (size_t)(b * HQ_ + hq) * (M_ * S_);
    short8 aq[8];
#pragma unroll
    for (int ks = 0; ks < 8; ++ks)
        aq[ks] = *reinterpret_cast<const short8*>(sqb + (size_t)l15 * S_ + ks * 32 + kgrp);
    __syncthreads();

    // ---- expansion: scol[n][s] = (sign ? +1 : -1) * bf16(cni[n]), overwrites abuf ----
    {
        const int n = tid & 63;
        const int c64 = tid >> 6;
        const unsigned short cb = f2bf_rne(snin[n]);
        const unsigned base = (unsigned)cb | ((unsigned)cb << 16);
        const int g = (n >> 2) & 3;
        const int r = n & 3;
        const int w = n >> 4;
        const int swz = (n & 7) << 3;
#pragma unroll
        for (int i = 0; i < 4; ++i) {
            const int t = c64 * 4 + i;
            const unsigned long long wd = words[w][t][r];
            const unsigned bits = (unsigned)(wd >> (16 * g)) & 0xFFFFu;
            const unsigned nb = ~bits;
            unsigned o[8];
#pragma unroll
            for (int p = 0; p < 8; ++p) {
                const unsigned m = (((nb >> (2 * p)) & 1u) << 15) |
                                   (((nb >> (2 * p + 1)) & 1u) << 31);
                o[p] = base ^ m;
            }
            const int s0 = c64 * 64 + i * 16;
            const int e0 = n * 256 + (s0 ^ swz);
            const int e1 = n * 256 + ((s0 + 8) ^ swz);
            *reinterpret_cast<uint4_*>(&abuf[e0]) = (uint4_){o[0], o[1], o[2], o[3]};
            *reinterpret_cast<uint4_*>(&abuf[e1]) = (uint4_){o[4], o[5], o[6], o[7]};
        }
    }
    __syncthreads();

    // ---- phase D: out[n][m] = part2 + MFMA(sq_bf16, scol) ----
    {
        const float* qhead = q + (size_t)(b * HQ_ + hq) * (M_ * D_);
        const int m0 = (lane >> 4) << 2;
#pragma unroll
        for (int ct = 0; ct < 4; ++ct) {
            const int n = 16 * ct + l15;
            // part2 init (sparse outlier dot)
            const f32x4 s01 = *reinterpret_cast<const f32x4*>(&su2[n][0]);
            const f32x4 s23 = *reinterpret_cast<const f32x4*>(&su2[n][4]);
            const unsigned long long ip = sidxp[n];
            float a0 = 0.f, a1 = 0.f, a2 = 0.f, a3 = 0.f;
#pragma unroll
            for (int j = 0; j < O_; ++j) {
                const float uj = (j < 4) ? s01[j & 3] : s23[j & 3];
                const int ix = (int)((ip >> (8 * j)) & 0x7Fu);
                const float* qp = qhead + ix;
                a0 = fmaf(uj, qp[(m0 + 0) * D_], a0);
                a1 = fmaf(uj, qp[(m0 + 1) * D_], a1);
                a2 = fmaf(uj, qp[(m0 + 2) * D_], a2);
                a3 = fmaf(uj, qp[(m0 + 3) * D_], a3);
            }
            f32x4 acc = (f32x4){a0, a1, a2, a3};
            // part1 via MFMA over S=256
            const int nswz = (n & 7) << 3;
#pragma unroll
            for (int ks = 0; ks < 8; ++ks) {
                const int ei = n * 256 + ((ks * 32 + kgrp) ^ nswz);
                const short8 bs = *reinterpret_cast<const short8*>(&abuf[ei]);
                acc = __builtin_amdgcn_mfma_f32_16x16x32_bf16(aq[ks], bs, acc, 0, 0, 0);
            }
            float* ob = out + ((size_t)(b * HQ_ + hq) * N_ + (n0 + n)) * M_ + m0;
            *reinterpret_cast<f32x4*>(ob) = acc;
        }
    }
}

extern "C" void kernel_launch(void* const* d_in, const int* in_sizes, int n_in,
                              void* d_out, int out_size, void* d_ws, size_t ws_size,
                              hipStream_t stream) {
    const float* query = (const float*)d_in[0];  // [B][HQ][M][D]
    const float* data  = (const float*)d_in[1];  // [B][HK][N][D]
    const float* proj  = (const float*)d_in[2];  // [D][S]
    const int*   oidx  = (const int*)d_in[3];    // [B][HK][N][O]

    float* out = (float*)d_out;                  // [B][HQ][N][M]
    unsigned short* sqHi = (unsigned short*)d_ws;                          // 1 MB
    unsigned short* PtHi = (unsigned short*)((char*)d_ws + (1 << 20));     // 64 KB
    unsigned short* PtLo = (unsigned short*)((char*)d_ws + (1 << 20) + (64 << 10));
    float*          Pt32 = (float*)((char*)d_ws + (1 << 20) + (128 << 10)); // 128 KB

    qjl_prept<<<dim3(D_), dim3(S_), 0, stream>>>(proj, PtHi, PtLo, Pt32);
    qjl_sketch_q<<<dim3(B_ * HQ_), dim3(256), 0, stream>>>(query, proj, sqHi);
    qjl_main<<<dim3(N_ / TN, HK_, B_), dim3(256), 0, stream>>>(data, query, proj, oidx,
                                                               sqHi, PtHi, PtLo, Pt32, out);
}

// Round 6
// 250.876 us; speedup vs baseline: 5.9887x; 1.0143x over previous
//
#include <hip/hip_runtime.h>
#include <hip/hip_bf16.h>
#include <math.h>

namespace {
constexpr int B_ = 4, HQ_ = 32, HK_ = 8, G_ = 4, M_ = 16;
constexpr int N_ = 8192, D_ = 128, S_ = 256, O_ = 8;
constexpr int TN = 64;               // n-rows per block
constexpr float TAU = 1e-3f;         // |dot| below this -> exact fp64 sign recheck (~25 sigma)
}

typedef short short8 __attribute__((ext_vector_type(8)));
typedef float f32x4 __attribute__((ext_vector_type(4)));
typedef unsigned int uint4_ __attribute__((ext_vector_type(4)));

__device__ inline unsigned short f2bf_rne(float f) {
    unsigned u = __float_as_uint(f);
    u += 0x7FFF + ((u >> 16) & 1);
    return (unsigned short)(u >> 16);
}
__device__ inline float bf2f(unsigned short h) {
    return __uint_as_float(((unsigned)h) << 16);
}

// ---------------- kernel P-split: PtHi/PtLo[s][d] = bf16 hi/lo of P[d][s]; Pt32 fp32 ----
__global__ __launch_bounds__(256) void qjl_prept(const float* __restrict__ P,
                                                 unsigned short* __restrict__ PtHi,
                                                 unsigned short* __restrict__ PtLo,
                                                 float* __restrict__ Pt32) {
    const int d = blockIdx.x;      // 0..127
    const int s = threadIdx.x;     // 0..255
    const float f = P[d * S_ + s];
    const unsigned short hb = f2bf_rne(f);
    const float lof = f - bf2f(hb);
    PtHi[s * D_ + d] = hb;
    PtLo[s * D_ + d] = f2bf_rne(lof);
    Pt32[s * D_ + d] = f;
}

// ---------------- kernel A: sqHi[head][m][s] = bf16(q · P) ----------------
__global__ __launch_bounds__(256) void qjl_sketch_q(const float* __restrict__ q,
                                                    const float* __restrict__ P,
                                                    unsigned short* __restrict__ sqHi) {
    __shared__ float qs[M_][D_];
    const int tid = threadIdx.x;
    const size_t blk = blockIdx.x;  // b*HQ + hq
    const float* qb = q + blk * (size_t)(M_ * D_);
    for (int i = tid; i < M_ * D_ / 4; i += 256)
        reinterpret_cast<float4*>(&qs[0][0])[i] = reinterpret_cast<const float4*>(qb)[i];
    __syncthreads();
    float acc[M_];
#pragma unroll
    for (int m = 0; m < M_; ++m) acc[m] = 0.f;
    const int s = tid;
    for (int d = 0; d < D_; ++d) {
        const float pv = P[d * S_ + s];
#pragma unroll
        for (int m = 0; m < M_; ++m) acc[m] = fmaf(qs[m][d], pv, acc[m]);
    }
    unsigned short* ob = sqHi + blk * (size_t)(M_ * S_);
#pragma unroll
    for (int m = 0; m < M_; ++m) ob[m * S_ + s] = f2bf_rne(acc[m]);
}

// rare cooperative path: exact fp64 sign of k_in[row] . P[:,col]; all 64 lanes participate.
// Pt32 is fp32 P transposed [s][d] -> contiguous float2 per lane (no column gather).
__device__ __noinline__ float qjl_fix_coop(const float* __restrict__ drow,
                                           const float* __restrict__ Pt32,
                                           int col, unsigned long long ip,
                                           float a, int src) {
    const int lane = threadIdx.x & 63;
    const float2 dv = *reinterpret_cast<const float2*>(&drow[2 * lane]);
    const float2 pv = *reinterpret_cast<const float2*>(&Pt32[(size_t)col * D_ + 2 * lane]);
    double p = 0.0;
#pragma unroll
    for (int e = 0; e < 2; ++e) {
        const int d = 2 * lane + e;
        const float v = e ? dv.y : dv.x;
        const float pw = e ? pv.y : pv.x;
        bool isout = false;
#pragma unroll
        for (int j = 0; j < 8; ++j)
            isout = isout || (((unsigned)(ip >> (8 * j)) & 0xFFu) == (unsigned)d);
        if (!isout) p = fma((double)v, (double)pw, p);
    }
#pragma unroll
    for (int off = 1; off < 64; off <<= 1) p += __shfl_xor(p, off);
    if (lane == src) a = (p > 0.0) ? 1.f : -1.f;
    return a;
}

// ---------------- kernel B: main ----------------
// grid (N/TN, HK, B), block 256 (4 waves).
// Phase C: wave wv owns ALL 64 rows x cols [64wv, 64wv+64); B single-buffered (32 VGPR),
//          3 independent MFMA accumulator chains (hi.hi / hi.lo / lo.hi) for ILP.
// Phase D: wave wv owns head hq = hk*G + wv.
__global__ __launch_bounds__(256) void qjl_main(const float* __restrict__ data,
                                                const float* __restrict__ q,
                                                const float* __restrict__ P,
                                                const int* __restrict__ oidx,
                                                const unsigned short* __restrict__ sqHi,
                                                const unsigned short* __restrict__ PtHi,
                                                const unsigned short* __restrict__ PtLo,
                                                const float* __restrict__ Pt32,
                                                float* __restrict__ out) {
    // abuf: phases 0..C: hi = [0..8191], lo = [8192..16383]  (elem idx row*128+d, XOR-swz)
    //       phases expand..D: scol[64][256] bf16 = +/- cni[n]  (elem idx n*256+s, XOR-swz)
    __shared__ unsigned short abuf[16384];                 // 32 KB (phase-disjoint union)
    __shared__ unsigned long long words[4][16][4];         // 2 KB; [rowtile][t][r]
    __shared__ float su2[TN][O_];                          // sign_out-weighted u (pre-scaled)
    __shared__ unsigned long long sidxp[TN];               // 8 outlier idx bytes (0xFF = dup)
    __shared__ float sfull[TN];
    __shared__ float snin[TN];                             // c_in * ||k_in||
    __shared__ float snout[TN];                            // c_out * ||k_out||

    const int tid = threadIdx.x;
    const int lane = tid & 63;
    const int wv = tid >> 6;
    const int l15 = lane & 15;
    const int kgrp = (lane >> 4) << 3;
    const int nt = blockIdx.x, hk = blockIdx.y, b = blockIdx.z;
    const int n0 = nt * TN;
    const float* dbase = data + ((size_t)(b * HK_ + hk) * N_) * D_;

    // ---- phase 0: load data tile, bf16 hi/lo split into LDS, per-row sumsq ----
    {
        const int r = tid >> 2;   // row 0..63
        const int c = tid & 3;
        const float* drow = dbase + (size_t)(n0 + r) * D_;
        const int swz = (r & 7) << 3;
        float ssq = 0.f;
#pragma unroll
        for (int k = 0; k < 8; ++k) {
            const int f = c + 4 * k;          // float4 index; elems d = 4f..4f+3
            float4 v = reinterpret_cast<const float4*>(drow)[f];
            ssq += v.x * v.x + v.y * v.y + v.z * v.z + v.w * v.w;
            unsigned short h0 = f2bf_rne(v.x), h1 = f2bf_rne(v.y),
                           h2 = f2bf_rne(v.z), h3 = f2bf_rne(v.w);
            unsigned short l0 = f2bf_rne(v.x - bf2f(h0)), l1 = f2bf_rne(v.y - bf2f(h1)),
                           l2 = f2bf_rne(v.z - bf2f(h2)), l3 = f2bf_rne(v.w - bf2f(h3));
            const int ei = r * 128 + ((4 * f) ^ swz);
            unsigned long long hw = (unsigned long long)h0 | ((unsigned long long)h1 << 16) |
                                    ((unsigned long long)h2 << 32) | ((unsigned long long)h3 << 48);
            unsigned long long lw = (unsigned long long)l0 | ((unsigned long long)l1 << 16) |
                                    ((unsigned long long)l2 << 32) | ((unsigned long long)l3 << 48);
            *reinterpret_cast<unsigned long long*>(&abuf[ei]) = hw;
            *reinterpret_cast<unsigned long long*>(&abuf[8192 + ei]) = lw;
        }
        ssq += __shfl_xor(ssq, 1);
        ssq += __shfl_xor(ssq, 2);
        if (c == 0) sfull[r] = ssq;
    }
    __syncthreads();

    // ---- phase A: dedup outliers (exact values from global), zero them in LDS, norms ----
    if (tid < TN) {
        const int n = tid;
        const int* ob = oidx + ((size_t)(b * HK_ + hk) * N_ + n0 + n) * O_;
        const float* drow = dbase + (size_t)(n0 + n) * D_;
        int id[O_];
        int4 i0 = reinterpret_cast<const int4*>(ob)[0];
        int4 i1 = reinterpret_cast<const int4*>(ob)[1];
        id[0] = i0.x; id[1] = i0.y; id[2] = i0.z; id[3] = i0.w;
        id[4] = i1.x; id[5] = i1.y; id[6] = i1.z; id[7] = i1.w;
        const int swz = (n & 7) << 3;
        unsigned long long ip = 0;
        float so2 = 0.f;
#pragma unroll
        for (int j = 0; j < O_; ++j) {
            bool dup = false;
#pragma unroll
            for (int jj = 0; jj < O_; ++jj)
                if (jj < j) dup = dup || (id[jj] == id[j]);
            if (!dup) {
                const float v = drow[id[j]];
                so2 = fmaf(v, v, so2);
                ip |= (unsigned long long)(id[j] & 0xFF) << (8 * j);
                const int ei = n * 128 + (id[j] ^ swz);
                abuf[ei] = 0;          // hi = 0
                abuf[8192 + ei] = 0;   // lo = 0  -> k_in exactly
            } else {
                ip |= 0xFFull << (8 * j);
            }
        }
        sidxp[n] = ip;
        const float CIN = (float)(1.2533141373155003 / 256.0);
        const float COUT = (float)(1.2533141373155003 / 64.0);
        snin[n] = CIN * sqrtf(fmaxf(sfull[n] - so2, 0.f));
        snout[n] = COUT * sqrtf(so2);
    }
    __syncthreads();

    // ---- phase B: sign_out (fp64, exact values) -> su2 = u * cout*normout ----
    // No trailing barrier: su2 is only read in phase D (fenced by the expansion barriers);
    // phase C touches neither su2 nor anything B writes, so B and C interleave per-wave.
    {
        const int n = tid >> 2;
        const int c = tid & 3;
        const unsigned long long ip = sidxp[n];
        const float* drow = dbase + (size_t)(n0 + n) * D_;
        float u[O_], vv[O_];
        const float* pr[O_];
        bool val[O_];
#pragma unroll
        for (int j = 0; j < O_; ++j) {
            u[j] = 0.f;
            const unsigned bt = (unsigned)(ip >> (8 * j)) & 0xFFu;
            val[j] = (bt != 0xFFu);
            const int ix = (int)(bt & 0x7Fu);
            pr[j] = P + ix * S_;
            vv[j] = val[j] ? drow[ix] : 0.f;
        }
#pragma unroll
        for (int ch = 0; ch < 4; ++ch) {
            const int tc = c * 16 + ch * 4;
            float4 pj[O_];
#pragma unroll
            for (int j = 0; j < O_; ++j)
                pj[j] = *reinterpret_cast<const float4*>(pr[j] + tc);
#pragma unroll
            for (int e = 0; e < 4; ++e) {
                double cs = 0.0;
#pragma unroll
                for (int j = 0; j < O_; ++j)
                    cs = fma((double)vv[j], (double)pj[j][e], cs);
                const float sg = (cs > 0.0) ? 1.f : ((cs < 0.0) ? -1.f : 0.f);
#pragma unroll
                for (int j = 0; j < O_; ++j)
                    u[j] = fmaf(sg, pj[j][e], u[j]);
            }
        }
#pragma unroll
        for (int j = 0; j < O_; ++j) {
            u[j] += __shfl_xor(u[j], 1);
            u[j] += __shfl_xor(u[j], 2);
        }
        if (c == 0) {
            const float cno = snout[n];
#pragma unroll
            for (int j = 0; j < O_; ++j) su2[n][j] = val[j] ? u[j] * cno : 0.f;
        }
    }

    // ---- phase C: signs = sgn(k_in . P) via bf16 hi/lo MFMA, wave owns 64 cols ----
    // Single-buffered B (32 VGPR), 3 independent accumulator chains for MFMA ILP.
    {
        const int t0 = wv * 4;
#pragma unroll
        for (int ti = 0; ti < 4; ++ti) {
            const int t = t0 + ti;
            short8 bhi[4], blo[4];
            const size_t bo = (size_t)(16 * t + l15) * D_ + kgrp;
#pragma unroll
            for (int ks = 0; ks < 4; ++ks) {
                bhi[ks] = *reinterpret_cast<const short8*>(PtHi + bo + ks * 32);
                blo[ks] = *reinterpret_cast<const short8*>(PtLo + bo + ks * 32);
            }
#pragma unroll
            for (int rt = 0; rt < 4; ++rt) {
                const int arow = 16 * rt + l15;
                const int aswz = (arow & 7) << 3;
                short8 ahi[4], alo[4];
#pragma unroll
                for (int ks = 0; ks < 4; ++ks) {
                    const int ei = arow * 128 + ((ks * 32 + kgrp) ^ aswz);
                    ahi[ks] = *reinterpret_cast<const short8*>(&abuf[ei]);
                    alo[ks] = *reinterpret_cast<const short8*>(&abuf[8192 + ei]);
                }
                f32x4 ac1 = (f32x4){0.f, 0.f, 0.f, 0.f};
                f32x4 ac2 = (f32x4){0.f, 0.f, 0.f, 0.f};
                f32x4 ac3 = (f32x4){0.f, 0.f, 0.f, 0.f};
#pragma unroll
                for (int ks = 0; ks < 4; ++ks) {
                    ac1 = __builtin_amdgcn_mfma_f32_16x16x32_bf16(ahi[ks], bhi[ks], ac1, 0, 0, 0);
                    ac2 = __builtin_amdgcn_mfma_f32_16x16x32_bf16(ahi[ks], blo[ks], ac2, 0, 0, 0);
                    ac3 = __builtin_amdgcn_mfma_f32_16x16x32_bf16(alo[ks], bhi[ks], ac3, 0, 0, 0);
                }
                f32x4 a = (ac1 + ac2) + ac3;
                const float mn = fminf(fminf(fabsf(a[0]), fabsf(a[1])),
                                       fminf(fabsf(a[2]), fabsf(a[3])));
                if (__ballot(mn < TAU) != 0ull) {   // rare: ~1 cell per block
#pragma unroll
                    for (int r = 0; r < 4; ++r) {
                        unsigned long long low = __ballot(fabsf(a[r]) < TAU);
                        while (low) {
                            const int src = __ffsll((unsigned long long)low) - 1;
                            low &= low - 1;
                            const int row = 16 * rt + ((src >> 4) << 2) + r;
                            const int col = 16 * t + (src & 15);
                            a[r] = qjl_fix_coop(dbase + (size_t)(n0 + row) * D_, Pt32, col,
                                                sidxp[row], a[r], src);
                        }
                    }
                }
#pragma unroll
                for (int r = 0; r < 4; ++r) {
                    const unsigned long long bb = __ballot(a[r] > 0.f);
                    if (lane == 0) words[rt][t][r] = bb;
                }
            }
        }
    }

    // ---- phase D A-prefetch (global-only; expansion phase hides latency) ----
    const int hq = hk * G_ + wv;
    const unsigned short* sqb = sqHi + (size_t)(b * HQ_ + hq) * (M_ * S_);
    short8 aq[8];
#pragma unroll
    for (int ks = 0; ks < 8; ++ks)
        aq[ks] = *reinterpret_cast<const short8*>(sqb + (size_t)l15 * S_ + ks * 32 + kgrp);
    __syncthreads();

    // ---- expansion: scol[n][s] = (sign ? +1 : -1) * bf16(cni[n]), overwrites abuf ----
    {
        const int n = tid & 63;
        const int c64 = tid >> 6;
        const unsigned short cb = f2bf_rne(snin[n]);
        const unsigned base = (unsigned)cb | ((unsigned)cb << 16);
        const int g = (n >> 2) & 3;
        const int r = n & 3;
        const int w = n >> 4;
        const int swz = (n & 7) << 3;
#pragma unroll
        for (int i = 0; i < 4; ++i) {
            const int t = c64 * 4 + i;
            const unsigned long long wd = words[w][t][r];
            const unsigned bits = (unsigned)(wd >> (16 * g)) & 0xFFFFu;
            const unsigned nb = ~bits;
            unsigned o[8];
#pragma unroll
            for (int p = 0; p < 8; ++p) {
                const unsigned m = (((nb >> (2 * p)) & 1u) << 15) |
                                   (((nb >> (2 * p + 1)) & 1u) << 31);
                o[p] = base ^ m;
            }
            const int s0 = c64 * 64 + i * 16;
            const int e0 = n * 256 + (s0 ^ swz);
            const int e1 = n * 256 + ((s0 + 8) ^ swz);
            *reinterpret_cast<uint4_*>(&abuf[e0]) = (uint4_){o[0], o[1], o[2], o[3]};
            *reinterpret_cast<uint4_*>(&abuf[e1]) = (uint4_){o[4], o[5], o[6], o[7]};
        }
    }
    __syncthreads();

    // ---- phase D: out[n][m] = MFMA(sq_bf16, scol) + part2 (independent chains) ----
    {
        const float* qhead = q + (size_t)(b * HQ_ + hq) * (M_ * D_);
        const int m0 = (lane >> 4) << 2;
#pragma unroll
        for (int ct = 0; ct < 4; ++ct) {
            const int n = 16 * ct + l15;
            const int nswz = (n & 7) << 3;
            // part1 via MFMA over S=256 (acc starts at 0; independent of part2 gathers)
            f32x4 acc = (f32x4){0.f, 0.f, 0.f, 0.f};
#pragma unroll
            for (int ks = 0; ks < 8; ++ks) {
                const int ei = n * 256 + ((ks * 32 + kgrp) ^ nswz);
                const short8 bs = *reinterpret_cast<const short8*>(&abuf[ei]);
                acc = __builtin_amdgcn_mfma_f32_16x16x32_bf16(aq[ks], bs, acc, 0, 0, 0);
            }
            // part2 (sparse outlier dot) in parallel scalar chain
            const f32x4 s01 = *reinterpret_cast<const f32x4*>(&su2[n][0]);
            const f32x4 s23 = *reinterpret_cast<const f32x4*>(&su2[n][4]);
            const unsigned long long ip = sidxp[n];
            float a0 = 0.f, a1 = 0.f, a2 = 0.f, a3 = 0.f;
#pragma unroll
            for (int j = 0; j < O_; ++j) {
                const float uj = (j < 4) ? s01[j & 3] : s23[j & 3];
                const int ix = (int)((ip >> (8 * j)) & 0x7Fu);
                const float* qp = qhead + ix;
                a0 = fmaf(uj, qp[(m0 + 0) * D_], a0);
                a1 = fmaf(uj, qp[(m0 + 1) * D_], a1);
                a2 = fmaf(uj, qp[(m0 + 2) * D_], a2);
                a3 = fmaf(uj, qp[(m0 + 3) * D_], a3);
            }
            acc[0] += a0; acc[1] += a1; acc[2] += a2; acc[3] += a3;
            float* ob = out + ((size_t)(b * HQ_ + hq) * N_ + (n0 + n)) * M_ + m0;
            *reinterpret_cast<f32x4*>(ob) = acc;
        }
    }
}

extern "C" void kernel_launch(void* const* d_in, const int* in_sizes, int n_in,
                              void* d_out, int out_size, void* d_ws, size_t ws_size,
                              hipStream_t stream) {
    const float* query = (const float*)d_in[0];  // [B][HQ][M][D]
    const float* data  = (const float*)d_in[1];  // [B][HK][N][D]
    const float* proj  = (const float*)d_in[2];  // [D][S]
    const int*   oidx  = (const int*)d_in[3];    // [B][HK][N][O]

    float* out = (float*)d_out;                  // [B][HQ][N][M]
    unsigned short* sqHi = (unsigned short*)d_ws;                          // 1 MB
    unsigned short* PtHi = (unsigned short*)((char*)d_ws + (1 << 20));     // 64 KB
    unsigned short* PtLo = (unsigned short*)((char*)d_ws + (1 << 20) + (64 << 10));
    float*          Pt32 = (float*)((char*)d_ws + (1 << 20) + (128 << 10)); // 128 KB

    qjl_prept<<<dim3(D_), dim3(S_), 0, stream>>>(proj, PtHi, PtLo, Pt32);
    qjl_sketch_q<<<dim3(B_ * HQ_), dim3(256), 0, stream>>>(query, proj, sqHi);
    qjl_main<<<dim3(N_ / TN, HK_, B_), dim3(256), 0, stream>>>(data, query, proj, oidx,
                                                               sqHi, PtHi, PtLo, Pt32, out);
}

// Round 7
// 214.971 us; speedup vs baseline: 6.9889x; 1.1670x over previous
//
#include <hip/hip_runtime.h>
#include <hip/hip_bf16.h>
#include <math.h>

namespace {
constexpr int B_ = 4, HQ_ = 32, HK_ = 8, G_ = 4, M_ = 16;
constexpr int N_ = 8192, D_ = 128, S_ = 256, O_ = 8;
constexpr int TN = 64;               // n-rows per block
constexpr float TAU  = 1e-3f;        // inlier sign: |dot| below -> exact fp64 recheck
constexpr float TAUO = 1e-4f;        // outlier sign: |dot| below -> exact fp64 recheck
}

typedef short short8 __attribute__((ext_vector_type(8)));
typedef float f32x4 __attribute__((ext_vector_type(4)));
typedef unsigned int uint4_ __attribute__((ext_vector_type(4)));
typedef unsigned long long ull2 __attribute__((ext_vector_type(2)));

__device__ inline unsigned short f2bf_rne(float f) {
    unsigned u = __float_as_uint(f);
    u += 0x7FFF + ((u >> 16) & 1);
    return (unsigned short)(u >> 16);
}
__device__ inline float bf2f(unsigned short h) {
    return __uint_as_float(((unsigned)h) << 16);
}

// ---------------- kernel P-split: PtHi/PtLo[s][d] = bf16 hi/lo of P[d][s]; Pt32 fp32 ----
__global__ __launch_bounds__(256) void qjl_prept(const float* __restrict__ P,
                                                 unsigned short* __restrict__ PtHi,
                                                 unsigned short* __restrict__ PtLo,
                                                 float* __restrict__ Pt32) {
    const int d = blockIdx.x;      // 0..127
    const int s = threadIdx.x;     // 0..255
    const float f = P[d * S_ + s];
    const unsigned short hb = f2bf_rne(f);
    const float lof = f - bf2f(hb);
    PtHi[s * D_ + d] = hb;
    PtLo[s * D_ + d] = f2bf_rne(lof);
    Pt32[s * D_ + d] = f;
}

// ---------------- kernel A: sqHi[head][m][s] = bf16(q · P); qT[head][d][m] = q^T ----
__global__ __launch_bounds__(256) void qjl_sketch_q(const float* __restrict__ q,
                                                    const float* __restrict__ P,
                                                    unsigned short* __restrict__ sqHi,
                                                    float* __restrict__ qT) {
    __shared__ float qs[M_][D_];
    const int tid = threadIdx.x;
    const size_t blk = blockIdx.x;  // b*HQ + hq
    const float* qb = q + blk * (size_t)(M_ * D_);
    for (int i = tid; i < M_ * D_ / 4; i += 256)
        reinterpret_cast<float4*>(&qs[0][0])[i] = reinterpret_cast<const float4*>(qb)[i];
    __syncthreads();
    // qT write: [d][m] fp32 (for kernel2's contiguous outlier gathers)
    float* qtb = qT + blk * (size_t)(D_ * M_);
    for (int i = tid; i < D_ * M_ / 4; i += 256) {
        const int d = i >> 2;
        const int m4 = i & 3;
        float4 v;
        v.x = qs[m4 * 4 + 0][d];
        v.y = qs[m4 * 4 + 1][d];
        v.z = qs[m4 * 4 + 2][d];
        v.w = qs[m4 * 4 + 3][d];
        reinterpret_cast<float4*>(qtb)[i] = v;
    }
    float acc[M_];
#pragma unroll
    for (int m = 0; m < M_; ++m) acc[m] = 0.f;
    const int s = tid;
    for (int d = 0; d < D_; ++d) {
        const float pv = P[d * S_ + s];
#pragma unroll
        for (int m = 0; m < M_; ++m) acc[m] = fmaf(qs[m][d], pv, acc[m]);
    }
    unsigned short* ob = sqHi + blk * (size_t)(M_ * S_);
#pragma unroll
    for (int m = 0; m < M_; ++m) ob[m * S_ + s] = f2bf_rne(acc[m]);
}

// rare cooperative path: exact fp64 sign of k_in[row] . P[:,col]; all 64 lanes participate.
__device__ __noinline__ float qjl_fix_coop(const float* __restrict__ drow,
                                           const float* __restrict__ Pt32,
                                           int col, unsigned long long ip,
                                           float a, int src) {
    const int lane = threadIdx.x & 63;
    const float2 dv = *reinterpret_cast<const float2*>(&drow[2 * lane]);
    const float2 pv = *reinterpret_cast<const float2*>(&Pt32[(size_t)col * D_ + 2 * lane]);
    double p = 0.0;
#pragma unroll
    for (int e = 0; e < 2; ++e) {
        const int d = 2 * lane + e;
        const float v = e ? dv.y : dv.x;
        const float pw = e ? pv.y : pv.x;
        bool isout = false;
#pragma unroll
        for (int j = 0; j < 8; ++j)
            isout = isout || (((unsigned)(ip >> (8 * j)) & 0xFFu) == (unsigned)d);
        if (!isout) p = fma((double)v, (double)pw, p);
    }
#pragma unroll
    for (int off = 1; off < 64; off <<= 1) p += __shfl_xor(p, off);
    if (lane == src) a = (p > 0.0) ? 1.f : -1.f;
    return a;
}

// ---------------- kernel 1: signs + norms + outlier state ----------------
// grid (N/TN, HK, B), block 256 (4 waves). Phase C: wave wv owns all 64 rows x
// cols [64wv,64wv+64). Writes per-row state to ws for kernel 2.
__global__ __launch_bounds__(256) void qjl_signs(const float* __restrict__ data,
                                                 const float* __restrict__ P,
                                                 const int* __restrict__ oidx,
                                                 const unsigned short* __restrict__ PtHi,
                                                 const unsigned short* __restrict__ PtLo,
                                                 const float* __restrict__ Pt32,
                                                 unsigned long long* __restrict__ wordsg,
                                                 float* __restrict__ sning,
                                                 float* __restrict__ su2g,
                                                 unsigned long long* __restrict__ sidxpg) {
    __shared__ unsigned short abuf[16384];        // 32 KB: hi [0..8191], lo [8192..], XOR-swz
    __shared__ unsigned long long sidxp[TN];
    __shared__ float sfull[TN];
    __shared__ float snout[TN];

    const int tid = threadIdx.x;
    const int lane = tid & 63;
    const int wv = tid >> 6;
    const int l15 = lane & 15;
    const int kgrp = (lane >> 4) << 3;
    const int nt = blockIdx.x, hk = blockIdx.y, b = blockIdx.z;
    const int n0 = nt * TN;
    const size_t rowbase = (size_t)(b * HK_ + hk) * N_ + n0;
    const size_t wblk = (size_t)((b * HK_ + hk) * (N_ / TN) + nt);
    const float* dbase = data + ((size_t)(b * HK_ + hk) * N_) * D_;

    // ---- phase 0: load data tile, bf16 hi/lo split into LDS, per-row sumsq ----
    {
        const int r = tid >> 2;
        const int c = tid & 3;
        const float* drow = dbase + (size_t)(n0 + r) * D_;
        const int swz = (r & 7) << 3;
        float ssq = 0.f;
#pragma unroll
        for (int k = 0; k < 8; ++k) {
            const int f = c + 4 * k;
            float4 v = reinterpret_cast<const float4*>(drow)[f];
            ssq += v.x * v.x + v.y * v.y + v.z * v.z + v.w * v.w;
            unsigned short h0 = f2bf_rne(v.x), h1 = f2bf_rne(v.y),
                           h2 = f2bf_rne(v.z), h3 = f2bf_rne(v.w);
            unsigned short l0 = f2bf_rne(v.x - bf2f(h0)), l1 = f2bf_rne(v.y - bf2f(h1)),
                           l2 = f2bf_rne(v.z - bf2f(h2)), l3 = f2bf_rne(v.w - bf2f(h3));
            const int ei = r * 128 + ((4 * f) ^ swz);
            unsigned long long hw = (unsigned long long)h0 | ((unsigned long long)h1 << 16) |
                                    ((unsigned long long)h2 << 32) | ((unsigned long long)h3 << 48);
            unsigned long long lw = (unsigned long long)l0 | ((unsigned long long)l1 << 16) |
                                    ((unsigned long long)l2 << 32) | ((unsigned long long)l3 << 48);
            *reinterpret_cast<unsigned long long*>(&abuf[ei]) = hw;
            *reinterpret_cast<unsigned long long*>(&abuf[8192 + ei]) = lw;
        }
        ssq += __shfl_xor(ssq, 1);
        ssq += __shfl_xor(ssq, 2);
        if (c == 0) sfull[r] = ssq;
    }
    __syncthreads();

    // ---- phase A: dedup outliers, zero them in LDS, norms; write snin/sidxp out ----
    if (tid < TN) {
        const int n = tid;
        const int* ob = oidx + ((size_t)(b * HK_ + hk) * N_ + n0 + n) * O_;
        const float* drow = dbase + (size_t)(n0 + n) * D_;
        int id[O_];
        int4 i0 = reinterpret_cast<const int4*>(ob)[0];
        int4 i1 = reinterpret_cast<const int4*>(ob)[1];
        id[0] = i0.x; id[1] = i0.y; id[2] = i0.z; id[3] = i0.w;
        id[4] = i1.x; id[5] = i1.y; id[6] = i1.z; id[7] = i1.w;
        const int swz = (n & 7) << 3;
        unsigned long long ip = 0;
        float so2 = 0.f;
#pragma unroll
        for (int j = 0; j < O_; ++j) {
            bool dup = false;
#pragma unroll
            for (int jj = 0; jj < O_; ++jj)
                if (jj < j) dup = dup || (id[jj] == id[j]);
            if (!dup) {
                const float v = drow[id[j]];
                so2 = fmaf(v, v, so2);
                ip |= (unsigned long long)(id[j] & 0xFF) << (8 * j);
                const int ei = n * 128 + (id[j] ^ swz);
                abuf[ei] = 0;
                abuf[8192 + ei] = 0;
            } else {
                ip |= 0xFFull << (8 * j);
            }
        }
        sidxp[n] = ip;
        sidxpg[rowbase + n] = ip;
        const float CIN = (float)(1.2533141373155003 / 256.0);
        const float COUT = (float)(1.2533141373155003 / 64.0);
        sning[rowbase + n] = CIN * sqrtf(fmaxf(sfull[n] - so2, 0.f));
        snout[n] = COUT * sqrtf(so2);
    }
    __syncthreads();

    // ---- phase B: sign_out fp32 + rare exact fp64; write su2 out ----
    {
        const int n = tid >> 2;
        const int c = tid & 3;
        const unsigned long long ip = sidxp[n];
        const float* drow = dbase + (size_t)(n0 + n) * D_;
        float u[O_], vv[O_];
        const float* pr[O_];
        bool val[O_];
#pragma unroll
        for (int j = 0; j < O_; ++j) {
            u[j] = 0.f;
            const unsigned bt = (unsigned)(ip >> (8 * j)) & 0xFFu;
            val[j] = (bt != 0xFFu);
            const int ix = (int)(bt & 0x7Fu);
            pr[j] = P + ix * S_;
            vv[j] = val[j] ? drow[ix] : 0.f;
        }
#pragma unroll
        for (int ch = 0; ch < 4; ++ch) {
            const int tc = c * 16 + ch * 4;
            float4 pj[O_];
#pragma unroll
            for (int j = 0; j < O_; ++j)
                pj[j] = *reinterpret_cast<const float4*>(pr[j] + tc);
#pragma unroll
            for (int e = 0; e < 4; ++e) {
                float cs = 0.f;
#pragma unroll
                for (int j = 0; j < O_; ++j)
                    cs = fmaf(vv[j], pj[j][e], cs);
                float sg;
                if (fabsf(cs) < TAUO) {   // rare exact path
                    double cd = 0.0;
#pragma unroll
                    for (int j = 0; j < O_; ++j)
                        cd = fma((double)vv[j], (double)pj[j][e], cd);
                    sg = (cd > 0.0) ? 1.f : ((cd < 0.0) ? -1.f : 0.f);
                } else {
                    sg = (cs > 0.f) ? 1.f : -1.f;
                }
#pragma unroll
                for (int j = 0; j < O_; ++j)
                    u[j] = fmaf(sg, pj[j][e], u[j]);
            }
        }
#pragma unroll
        for (int j = 0; j < O_; ++j) {
            u[j] += __shfl_xor(u[j], 1);
            u[j] += __shfl_xor(u[j], 2);
        }
        if (c == 0) {
            const float cno = snout[n];
            float o[O_];
#pragma unroll
            for (int j = 0; j < O_; ++j) o[j] = val[j] ? u[j] * cno : 0.f;
            float* sp = su2g + (rowbase + n) * O_;
            *reinterpret_cast<f32x4*>(sp) = (f32x4){o[0], o[1], o[2], o[3]};
            *reinterpret_cast<f32x4*>(sp + 4) = (f32x4){o[4], o[5], o[6], o[7]};
        }
    }
    // no barrier: phase C reads abuf (stable since phase A's barrier)

    // ---- phase C: signs via bf16 hi/lo MFMA; raw ballot words -> global ----
    {
        const int t0 = wv * 4;
#pragma unroll
        for (int ti = 0; ti < 4; ++ti) {
            const int t = t0 + ti;
            short8 bhi[4], blo[4];
            const size_t bo = (size_t)(16 * t + l15) * D_ + kgrp;
#pragma unroll
            for (int ks = 0; ks < 4; ++ks) {
                bhi[ks] = *reinterpret_cast<const short8*>(PtHi + bo + ks * 32);
                blo[ks] = *reinterpret_cast<const short8*>(PtLo + bo + ks * 32);
            }
#pragma unroll
            for (int rt = 0; rt < 4; ++rt) {
                const int arow = 16 * rt + l15;
                const int aswz = (arow & 7) << 3;
                short8 ahi[4], alo[4];
#pragma unroll
                for (int ks = 0; ks < 4; ++ks) {
                    const int ei = arow * 128 + ((ks * 32 + kgrp) ^ aswz);
                    ahi[ks] = *reinterpret_cast<const short8*>(&abuf[ei]);
                    alo[ks] = *reinterpret_cast<const short8*>(&abuf[8192 + ei]);
                }
                f32x4 ac1 = (f32x4){0.f, 0.f, 0.f, 0.f};
                f32x4 ac2 = (f32x4){0.f, 0.f, 0.f, 0.f};
                f32x4 ac3 = (f32x4){0.f, 0.f, 0.f, 0.f};
#pragma unroll
                for (int ks = 0; ks < 4; ++ks) {
                    ac1 = __builtin_amdgcn_mfma_f32_16x16x32_bf16(ahi[ks], bhi[ks], ac1, 0, 0, 0);
                    ac2 = __builtin_amdgcn_mfma_f32_16x16x32_bf16(ahi[ks], blo[ks], ac2, 0, 0, 0);
                    ac3 = __builtin_amdgcn_mfma_f32_16x16x32_bf16(alo[ks], bhi[ks], ac3, 0, 0, 0);
                }
                f32x4 a = (ac1 + ac2) + ac3;
                const float mn = fminf(fminf(fabsf(a[0]), fabsf(a[1])),
                                       fminf(fabsf(a[2]), fabsf(a[3])));
                if (__ballot(mn < TAU) != 0ull) {   // rare
#pragma unroll
                    for (int r = 0; r < 4; ++r) {
                        unsigned long long low = __ballot(fabsf(a[r]) < TAU);
                        while (low) {
                            const int src = __ffsll((unsigned long long)low) - 1;
                            low &= low - 1;
                            const int row = 16 * rt + ((src >> 4) << 2) + r;
                            const int col = 16 * t + (src & 15);
                            a[r] = qjl_fix_coop(dbase + (size_t)(n0 + row) * D_, Pt32, col,
                                                sidxp[row], a[r], src);
                        }
                    }
                }
                unsigned long long bb0 = __ballot(a[0] > 0.f);
                unsigned long long bb1 = __ballot(a[1] > 0.f);
                unsigned long long bb2 = __ballot(a[2] > 0.f);
                unsigned long long bb3 = __ballot(a[3] > 0.f);
                if (lane == 0) {
                    unsigned long long* wp = wordsg + (wblk * 256 + (size_t)(rt * 16 + t) * 4);
                    *reinterpret_cast<ull2*>(wp) = (ull2){bb0, bb1};
                    *reinterpret_cast<ull2*>(wp + 2) = (ull2){bb2, bb3};
                }
            }
        }
    }
}

// ---------------- kernel 2: expand signs + output GEMM ----------------
// grid (N/TN, HK, B), block 256 (4 waves); wave wv owns head hq = hk*G + wv.
__global__ __launch_bounds__(256) void qjl_out(const unsigned short* __restrict__ sqHi,
                                               const float* __restrict__ qT,
                                               const unsigned long long* __restrict__ wordsg,
                                               const float* __restrict__ sning,
                                               const float* __restrict__ su2g,
                                               const unsigned long long* __restrict__ sidxpg,
                                               float* __restrict__ out) {
    __shared__ unsigned short scol[16384];       // 32 KB: [n][256] bf16 = +/- cni, XOR-swz

    const int tid = threadIdx.x;
    const int lane = tid & 63;
    const int wv = tid >> 6;
    const int l15 = lane & 15;
    const int kgrp = (lane >> 4) << 3;
    const int nt = blockIdx.x, hk = blockIdx.y, b = blockIdx.z;
    const int n0 = nt * TN;
    const size_t rowbase = (size_t)(b * HK_ + hk) * N_ + n0;
    const size_t wblk = (size_t)((b * HK_ + hk) * (N_ / TN) + nt);
    const int hq = hk * G_ + wv;

    // A-fragment prefetch (latency hidden under expansion)
    const unsigned short* sqb = sqHi + (size_t)(b * HQ_ + hq) * (M_ * S_);
    short8 aq[8];
#pragma unroll
    for (int ks = 0; ks < 8; ++ks)
        aq[ks] = *reinterpret_cast<const short8*>(sqb + (size_t)l15 * S_ + ks * 32 + kgrp);

    // ---- expansion: scol[n][s] = (sign ? +1 : -1) * bf16(cni[n]) ----
    {
        const int n = tid & 63;
        const int c64 = tid >> 6;
        const unsigned short cb = f2bf_rne(sning[rowbase + n]);
        const unsigned base = (unsigned)cb | ((unsigned)cb << 16);
        const int g = (n >> 2) & 3;
        const int r = n & 3;
        const int w = n >> 4;
        const int swz = (n & 7) << 3;
        const unsigned long long* wbp = wordsg + wblk * 256;
#pragma unroll
        for (int i = 0; i < 4; ++i) {
            const int t = c64 * 4 + i;
            const unsigned long long wd = wbp[(size_t)(w * 16 + t) * 4 + r];
            const unsigned bits = (unsigned)(wd >> (16 * g)) & 0xFFFFu;
            const unsigned nb = ~bits;
            unsigned o[8];
#pragma unroll
            for (int p = 0; p < 8; ++p) {
                const unsigned m = (((nb >> (2 * p)) & 1u) << 15) |
                                   (((nb >> (2 * p + 1)) & 1u) << 31);
                o[p] = base ^ m;
            }
            const int s0 = c64 * 64 + i * 16;
            const int e0 = n * 256 + (s0 ^ swz);
            const int e1 = n * 256 + ((s0 + 8) ^ swz);
            *reinterpret_cast<uint4_*>(&scol[e0]) = (uint4_){o[0], o[1], o[2], o[3]};
            *reinterpret_cast<uint4_*>(&scol[e1]) = (uint4_){o[4], o[5], o[6], o[7]};
        }
    }
    __syncthreads();

    // ---- GEMM + sparse part2 per wave/head ----
    {
        const float* qtb = qT + (size_t)(b * HQ_ + hq) * (D_ * M_);
        const int m0 = (lane >> 4) << 2;
#pragma unroll
        for (int ct = 0; ct < 4; ++ct) {
            const int n = 16 * ct + l15;
            const size_t row = rowbase + n;
            // issue per-row state loads early
            const unsigned long long ip = sidxpg[row];
            const f32x4 s01 = *reinterpret_cast<const f32x4*>(su2g + row * O_);
            const f32x4 s23 = *reinterpret_cast<const f32x4*>(su2g + row * O_ + 4);
            // part1 via MFMA over S=256
            const int nswz = (n & 7) << 3;
            f32x4 acc = (f32x4){0.f, 0.f, 0.f, 0.f};
#pragma unroll
            for (int ks = 0; ks < 8; ++ks) {
                const int ei = n * 256 + ((ks * 32 + kgrp) ^ nswz);
                const short8 bs = *reinterpret_cast<const short8*>(&scol[ei]);
                acc = __builtin_amdgcn_mfma_f32_16x16x32_bf16(aq[ks], bs, acc, 0, 0, 0);
            }
            // part2: contiguous float4 gathers from qT
            float a0 = 0.f, a1 = 0.f, a2 = 0.f, a3 = 0.f;
#pragma unroll
            for (int j = 0; j < O_; ++j) {
                const float uj = (j < 4) ? s01[j & 3] : s23[j & 3];
                const int ix = (int)((ip >> (8 * j)) & 0x7Fu);
                const float4 qv = *reinterpret_cast<const float4*>(qtb + ix * M_ + m0);
                a0 = fmaf(uj, qv.x, a0);
                a1 = fmaf(uj, qv.y, a1);
                a2 = fmaf(uj, qv.z, a2);
                a3 = fmaf(uj, qv.w, a3);
            }
            acc[0] += a0; acc[1] += a1; acc[2] += a2; acc[3] += a3;
            float* ob = out + ((size_t)(b * HQ_ + hq) * N_ + (n0 + n)) * M_ + m0;
            *reinterpret_cast<f32x4*>(ob) = acc;
        }
    }
}

extern "C" void kernel_launch(void* const* d_in, const int* in_sizes, int n_in,
                              void* d_out, int out_size, void* d_ws, size_t ws_size,
                              hipStream_t stream) {
    const float* query = (const float*)d_in[0];  // [B][HQ][M][D]
    const float* data  = (const float*)d_in[1];  // [B][HK][N][D]
    const float* proj  = (const float*)d_in[2];  // [D][S]
    const int*   oidx  = (const int*)d_in[3];    // [B][HK][N][O]

    float* out = (float*)d_out;                  // [B][HQ][N][M]

    char* ws = (char*)d_ws;
    unsigned short* sqHi  = (unsigned short*)(ws);                     // 1 MB
    float*          qT    = (float*)(ws + (1 << 20));                  // 1 MB
    unsigned short* PtHi  = (unsigned short*)(ws + (2 << 20));         // 64 KB
    unsigned short* PtLo  = (unsigned short*)(ws + (2 << 20) + (64 << 10));   // 64 KB
    float*          Pt32  = (float*)(ws + (2 << 20) + (128 << 10));    // 128 KB
    unsigned long long* wordsg = (unsigned long long*)(ws + (3 << 20)); // 8 MB
    float*          sning = (float*)(ws + (11 << 20));                 // 1 MB
    float*          su2g  = (float*)(ws + (12 << 20));                 // 8 MB
    unsigned long long* sidxpg = (unsigned long long*)(ws + (20 << 20)); // 2 MB

    qjl_prept<<<dim3(D_), dim3(S_), 0, stream>>>(proj, PtHi, PtLo, Pt32);
    qjl_sketch_q<<<dim3(B_ * HQ_), dim3(256), 0, stream>>>(query, proj, sqHi, qT);
    qjl_signs<<<dim3(N_ / TN, HK_, B_), dim3(256), 0, stream>>>(
        data, proj, oidx, PtHi, PtLo, Pt32, wordsg, sning, su2g, sidxpg);
    qjl_out<<<dim3(N_ / TN, HK_, B_), dim3(256), 0, stream>>>(
        sqHi, qT, wordsg, sning, su2g, sidxpg, out);
}